// Round 1
// baseline (5115.030 us; speedup 1.0000x reference)
//
#include <hip/hip_runtime.h>

#define N_    384
#define E_    3072
#define CIN_  4096
#define EMB_  200
#define D_    512
#define NOBJ_ 151
#define NREL_ 51
#define K1_   (CIN_ + EMB_ + 128)   // 4424 node_emb K
#define K2_   (CIN_ + EMB_ + D_)    // 4808 node_emb2 K

// ---------------- pair dedup ----------------
// mapMin[i*N+j] = min edge index hitting cell (i,j); memset 0x7F = big int.
__global__ void k_pair_min(const int* __restrict__ rp, int* __restrict__ mapMin) {
    int e = blockIdx.x * blockDim.x + threadIdx.x;
    if (e >= E_) return;
    atomicMin(&mapMin[rp[2 * e] * N_ + rp[2 * e + 1]], e);
}
__global__ void k_pair_rep(const int* __restrict__ rp, const int* __restrict__ mapMin,
                           int* __restrict__ rep, int* __restrict__ deg_cnt) {
    int e = blockIdx.x * blockDim.x + threadIdx.x;
    if (e >= E_) return;
    int r = mapMin[rp[2 * e] * N_ + rp[2 * e + 1]];
    rep[e] = r;
    if (r == e) atomicAdd(&deg_cnt[rp[2 * e]], 1);  // distinct-pair out-degree
}
__global__ void k_inv_deg(const int* __restrict__ deg_cnt, float* __restrict__ inv_deg) {
    int i = blockIdx.x * blockDim.x + threadIdx.x;
    if (i < N_) inv_deg[i] = 1.0f / ((float)deg_cnt[i] + 1e-6f);
}

// ---------------- pos MLP + batchnorm (tiny) ----------------
__global__ void k_pos1(const float* __restrict__ pi, const float* __restrict__ w,
                       const float* __restrict__ b, float* __restrict__ ph) {
    int idx = blockIdx.x * blockDim.x + threadIdx.x;
    if (idx >= N_ * 32) return;
    int i = idx / 32, f = idx % 32;
    float s = b[f];
    for (int k = 0; k < 9; ++k) s += pi[i * 9 + k] * w[f * 9 + k];
    ph[idx] = s;
}
__global__ void k_pos_stats(const float* __restrict__ ph, float* __restrict__ mu,
                            float* __restrict__ rstd) {
    int f = threadIdx.x;
    if (f >= 32) return;
    float s = 0.f;
    for (int i = 0; i < N_; ++i) s += ph[i * 32 + f];
    float m = s / N_;
    float v = 0.f;
    for (int i = 0; i < N_; ++i) { float d = ph[i * 32 + f] - m; v += d * d; }
    v /= N_;
    mu[f] = m;
    rstd[f] = rsqrtf(v + 1e-5f);
}
__global__ void k_pos_norm(const float* __restrict__ ph, const float* __restrict__ mu,
                           const float* __restrict__ rstd, const float* __restrict__ g,
                           const float* __restrict__ be, float* __restrict__ out) {
    int idx = blockIdx.x * blockDim.x + threadIdx.x;
    if (idx >= N_ * 32) return;
    int f = idx % 32;
    out[idx] = (ph[idx] - mu[f]) * rstd[f] * g[f] + be[f];
}
__global__ void k_pos2(const float* __restrict__ pn, const float* __restrict__ w,
                       const float* __restrict__ b, float* __restrict__ out) {
    int idx = blockIdx.x * blockDim.x + threadIdx.x;
    if (idx >= N_ * 128) return;
    int i = idx / 128, f = idx % 128;
    float s = b[f];
    for (int k = 0; k < 32; ++k) s += pn[i * 32 + k] * w[f * 32 + k];
    out[idx] = fmaxf(s, 0.f);
}

// ---------------- concat builders ----------------
__global__ void k_build_A1(const float* __restrict__ x, const int* __restrict__ lab,
                           const float* __restrict__ emb1, const float* __restrict__ pe,
                           float* __restrict__ A) {
    int idx = blockIdx.x * blockDim.x + threadIdx.x;
    if (idx >= N_ * K1_) return;
    int i = idx / K1_, c = idx % K1_;
    float v;
    if (c < CIN_)            v = x[(size_t)i * CIN_ + c];
    else if (c < CIN_ + EMB_) v = emb1[lab[i] * EMB_ + (c - CIN_)];
    else                      v = pe[i * 128 + (c - CIN_ - EMB_)];
    A[idx] = v;
}
__global__ void k_build_A2(const float* __restrict__ x, const int* __restrict__ lab,
                           const float* __restrict__ emb2, const float* __restrict__ ns,
                           float* __restrict__ A) {
    int idx = blockIdx.x * blockDim.x + threadIdx.x;
    if (idx >= N_ * K2_) return;
    int i = idx / K2_, c = idx % K2_;
    float v;
    if (c < CIN_)             v = x[(size_t)i * CIN_ + c];
    else if (c < CIN_ + D_)   v = ns[i * D_ + (c - CIN_)];
    else                      v = emb2[lab[i] * EMB_ + (c - CIN_ - D_)];
    A[idx] = v;
}
__global__ void k_build_ek(const int* __restrict__ rp, const float* __restrict__ ns,
                           float* __restrict__ ek) {
    int idx = blockIdx.x * blockDim.x + threadIdx.x;
    if (idx >= E_ * 2 * D_) return;
    int e = idx / (2 * D_), c = idx % (2 * D_);
    float v = (c < D_) ? ns[rp[2 * e] * D_ + c] : ns[rp[2 * e + 1] * D_ + (c - D_)];
    ek[idx] = v;
}

// ---------------- scatter / pointwise ----------------
__global__ void k_scatter_edge(const float* __restrict__ er, const int* __restrict__ rep,
                               float* __restrict__ es) {
    int e = blockIdx.x;
    int d = blockIdx.y * 256 + threadIdx.x;
    atomicAdd(&es[(size_t)rep[e] * D_ + d], er[(size_t)e * D_ + d]);
}
__global__ void k_broadcast_es(const int* __restrict__ rep, float* __restrict__ es) {
    int idx = blockIdx.x * blockDim.x + threadIdx.x;
    if (idx >= E_ * D_) return;
    int e = idx / D_, d = idx % D_;
    es[idx] = es[(size_t)rep[e] * D_ + d];  // rep rows rewrite own value; dup rows only read reps
}
__global__ void k_scatter_e2n(const int* __restrict__ rp, const int* __restrict__ rep,
                              const float* __restrict__ es, float* __restrict__ e2n) {
    int e = blockIdx.x;
    if (rep[e] != e) return;
    int d = blockIdx.y * 256 + threadIdx.x;
    atomicAdd(&e2n[rp[2 * e + 1] * D_ + d], es[(size_t)e * D_ + d]);
}
__global__ void k_scatter_n2n(const int* __restrict__ rp, const int* __restrict__ rep,
                              const float* __restrict__ ns, float* __restrict__ n2n) {
    int e = blockIdx.x;
    if (rep[e] != e) return;
    int d = blockIdx.y * 256 + threadIdx.x;
    atomicAdd(&n2n[rp[2 * e] * D_ + d], ns[rp[2 * e + 1] * D_ + d]);
}
__global__ void k_scale_rows(float* __restrict__ a, const float* __restrict__ inv_deg) {
    int idx = blockIdx.x * blockDim.x + threadIdx.x;
    if (idx >= N_ * D_) return;
    a[idx] *= inv_deg[idx / D_];
}
__global__ void k_combine(const float* __restrict__ a, const float* __restrict__ b,
                          float* __restrict__ o) {
    int idx = blockIdx.x * blockDim.x + threadIdx.x;
    if (idx >= N_ * D_) return;
    o[idx] = 0.5f * a[idx] + 0.5f * b[idx];   // ALPHA = 0.5
}
__global__ void k_gru(const float* __restrict__ gi, const float* __restrict__ gh,
                      const float* __restrict__ bih, const float* __restrict__ bhh,
                      float* __restrict__ h, int M) {
    int idx = blockIdx.x * blockDim.x + threadIdx.x;
    if (idx >= M * D_) return;
    int m = idx / D_, d = idx % D_;
    size_t b3 = (size_t)m * 3 * D_;
    float ir = gi[b3 + d], iz = gi[b3 + D_ + d], ig = gi[b3 + 2 * D_ + d];
    float hr = gh[b3 + d], hz = gh[b3 + D_ + d], hg = gh[b3 + 2 * D_ + d];
    if (bih) { ir += bih[d]; iz += bih[D_ + d]; ig += bih[2 * D_ + d]; }
    if (bhh) { hr += bhh[d]; hz += bhh[D_ + d]; hg += bhh[2 * D_ + d]; }
    float r = 1.f / (1.f + expf(-(ir + hr)));
    float z = 1.f / (1.f + expf(-(iz + hz)));
    float g = tanhf(ig + r * hg);
    size_t hi = (size_t)m * D_ + d;
    h[hi] = (1.f - z) * g + z * h[hi];   // pointwise -> in-place safe
}
__global__ void k_obj_dists(const int* __restrict__ lab, float* __restrict__ out) {
    int idx = blockIdx.x * blockDim.x + threadIdx.x;
    if (idx >= N_ * NOBJ_) return;
    out[idx] = (idx % NOBJ_ == lab[idx / NOBJ_]) ? 1000.f : -1000.f;
}

// ---------------- generic f32 NT GEMM: C[M,N] = A[M,K] @ B[N,K]^T (+bias)(relu) ----------------
#define TM 64
#define TN 64
#define TK 16
__global__ __launch_bounds__(256) void gemm_nt(const float* __restrict__ A,
                                               const float* __restrict__ B,
                                               const float* __restrict__ bias,
                                               float* __restrict__ C,
                                               int M, int N, int K, int relu) {
    __shared__ float As[TK][TM];
    __shared__ float Bs[TK][TN];
    int tid = threadIdx.x;
    int tx = tid % 16, ty = tid / 16;
    int bm = blockIdx.y * TM, bn = blockIdx.x * TN;
    float acc[4][4] = {};
    for (int k0 = 0; k0 < K; k0 += TK) {
        for (int l = tid; l < TM * TK; l += 256) {
            int m = l / TK, k = l % TK;            // consecutive tid -> consecutive k (coalesced)
            float v = 0.f;
            if (bm + m < M && k0 + k < K) v = A[(size_t)(bm + m) * K + k0 + k];
            As[k][m] = v;
        }
        for (int l = tid; l < TN * TK; l += 256) {
            int n = l / TK, k = l % TK;
            float v = 0.f;
            if (bn + n < N && k0 + k < K) v = B[(size_t)(bn + n) * K + k0 + k];
            Bs[k][n] = v;
        }
        __syncthreads();
#pragma unroll
        for (int k = 0; k < TK; ++k) {
            float a[4], b[4];
#pragma unroll
            for (int i = 0; i < 4; ++i) a[i] = As[k][ty * 4 + i];
#pragma unroll
            for (int j = 0; j < 4; ++j) b[j] = Bs[k][tx * 4 + j];
#pragma unroll
            for (int i = 0; i < 4; ++i)
#pragma unroll
                for (int j = 0; j < 4; ++j) acc[i][j] += a[i] * b[j];
        }
        __syncthreads();
    }
    for (int i = 0; i < 4; ++i) {
        int m = bm + ty * 4 + i;
        if (m >= M) continue;
        for (int j = 0; j < 4; ++j) {
            int n = bn + tx * 4 + j;
            if (n >= N) continue;
            float v = acc[i][j] + (bias ? bias[n] : 0.f);
            if (relu) v = fmaxf(v, 0.f);
            C[(size_t)m * N + n] = v;
        }
    }
}

static inline dim3 ggrid(int M, int N) { return dim3((N + TN - 1) / TN, (M + TM - 1) / TM); }

extern "C" void kernel_launch(void* const* d_in, const int* in_sizes, int n_in,
                              void* d_out, int out_size, void* d_ws, size_t ws_size,
                              hipStream_t stream) {
    const float* x      = (const float*)d_in[0];
    const float* posi   = (const float*)d_in[1];
    const float* unionf = (const float*)d_in[2];
    const int*   lab    = (const int*)d_in[3];
    const int*   rp     = (const int*)d_in[4];
    const float* emb1   = (const float*)d_in[5];
    const float* emb2   = (const float*)d_in[6];
    const float* nw     = (const float*)d_in[7];
    const float* nb     = (const float*)d_in[8];
    const float* nw2    = (const float*)d_in[9];
    const float* nb2    = (const float*)d_in[10];
    const float* ew     = (const float*)d_in[11];
    const float* eb     = (const float*)d_in[12];
    const float* pw1    = (const float*)d_in[13];
    const float* pb1    = (const float*)d_in[14];
    const float* pg     = (const float*)d_in[15];
    const float* pbe    = (const float*)d_in[16];
    const float* pw2    = (const float*)d_in[17];
    const float* pb2    = (const float*)d_in[18];
    const float* ngwih  = (const float*)d_in[19];
    const float* ngwhh  = (const float*)d_in[20];
    const float* ngbih  = (const float*)d_in[21];
    const float* ngbhh  = (const float*)d_in[22];
    const float* egwih  = (const float*)d_in[23];
    const float* egwhh  = (const float*)d_in[24];
    const float* n2nw1  = (const float*)d_in[25];
    const float* n2nb1  = (const float*)d_in[26];
    const float* n2nw2  = (const float*)d_in[27];
    const float* n2nb2  = (const float*)d_in[28];
    const float* e2nw1  = (const float*)d_in[29];
    const float* e2nb1  = (const float*)d_in[30];
    const float* e2nw2  = (const float*)d_in[31];
    const float* e2nb2  = (const float*)d_in[32];
    const float* n2ew1  = (const float*)d_in[33];
    const float* n2eb1  = (const float*)d_in[34];
    const float* n2ew2  = (const float*)d_in[35];
    const float* n2eb2  = (const float*)d_in[36];
    const float* relw   = (const float*)d_in[37];
    const float* relb   = (const float*)d_in[38];

    // ---- workspace layout (256B aligned) ----
    size_t off = 0;
    auto alloc = [&](size_t bytes) {
        off = (off + 255) & ~(size_t)255;
        char* p = (char*)d_ws + off;
        off += bytes;
        return (void*)p;
    };
    int*   mapMin  = (int*)alloc((size_t)N_ * N_ * 4);
    int*   rep     = (int*)alloc(E_ * 4);
    int*   deg_cnt = (int*)alloc(N_ * 4);
    float* inv_deg = (float*)alloc(N_ * 4);
    float* ph      = (float*)alloc(N_ * 32 * 4);
    float* mu      = (float*)alloc(32 * 4);
    float* rstd    = (float*)alloc(32 * 4);
    float* posn    = (float*)alloc(N_ * 32 * 4);
    float* pe      = (float*)alloc(N_ * 128 * 4);
    float* Abig    = (float*)alloc((size_t)E_ * 2 * D_ * 4);   // A1 / A2 / ek share
    float* ns      = (float*)alloc(N_ * D_ * 4);
    float* erep    = (float*)alloc((size_t)E_ * D_ * 4);       // edge_rep, reused as t1e
    float* es      = (float*)alloc((size_t)E_ * D_ * 4);
    float* msg     = (float*)alloc((size_t)E_ * D_ * 4);
    float* gie     = (float*)alloc((size_t)E_ * 3 * D_ * 4);
    float* ghe     = (float*)alloc((size_t)E_ * 3 * D_ * 4);
    float* e2n     = (float*)alloc(N_ * D_ * 4);
    float* e2nm    = (float*)alloc(N_ * D_ * 4);
    float* n2n     = (float*)alloc(N_ * D_ * 4);
    float* n2nm    = (float*)alloc(N_ * D_ * 4);
    float* tmpn    = (float*)alloc(N_ * D_ * 4);
    float* xin     = (float*)alloc(N_ * D_ * 4);
    float* gin     = (float*)alloc(N_ * 3 * D_ * 4);
    float* ghn     = (float*)alloc(N_ * 3 * D_ * 4);
    if (off > ws_size) return;  // workspace too small -> visible validation failure

    float* out_obj = (float*)d_out;
    float* out_rel = (float*)d_out + N_ * NOBJ_;

    // ---- pair dedup + degrees ----
    (void)hipMemsetAsync(mapMin, 0x7F, (size_t)N_ * N_ * 4, stream);
    (void)hipMemsetAsync(deg_cnt, 0, N_ * 4, stream);
    k_pair_min<<<(E_ + 255) / 256, 256, 0, stream>>>(rp, mapMin);
    k_pair_rep<<<(E_ + 255) / 256, 256, 0, stream>>>(rp, mapMin, rep, deg_cnt);
    k_inv_deg<<<(N_ + 255) / 256, 256, 0, stream>>>(deg_cnt, inv_deg);

    // ---- pos embed ----
    k_pos1<<<(N_ * 32 + 255) / 256, 256, 0, stream>>>(posi, pw1, pb1, ph);
    k_pos_stats<<<1, 64, 0, stream>>>(ph, mu, rstd);
    k_pos_norm<<<(N_ * 32 + 255) / 256, 256, 0, stream>>>(ph, mu, rstd, pg, pbe, posn);
    k_pos2<<<(N_ * 128 + 255) / 256, 256, 0, stream>>>(posn, pw2, pb2, pe);

    // ---- node_states = [x|emb1|pos] @ nw^T + nb ----
    k_build_A1<<<((size_t)N_ * K1_ + 255) / 256, 256, 0, stream>>>(x, lab, emb1, pe, Abig);
    gemm_nt<<<ggrid(N_, D_), 256, 0, stream>>>(Abig, nw, nb, ns, N_, D_, K1_, 0);

    // ---- edge_rep + sparse edge_states ----
    gemm_nt<<<ggrid(E_, D_), 256, 0, stream>>>(unionf, ew, eb, erep, E_, D_, CIN_, 0);
    (void)hipMemsetAsync(es, 0, (size_t)E_ * D_ * 4, stream);
    k_scatter_edge<<<dim3(E_, 2), 256, 0, stream>>>(erep, rep, es);
    k_broadcast_es<<<(E_ * D_ + 255) / 256, 256, 0, stream>>>(rep, es);

    // ---- e2n (loop-invariant in node loop): scatter + mlp2, once ----
    (void)hipMemsetAsync(e2n, 0, N_ * D_ * 4, stream);
    k_scatter_e2n<<<dim3(E_, 2), 256, 0, stream>>>(rp, rep, es, e2n);
    gemm_nt<<<ggrid(N_, D_), 256, 0, stream>>>(e2n, e2nw1, e2nb1, tmpn, N_, D_, D_, 1);
    gemm_nt<<<ggrid(N_, D_), 256, 0, stream>>>(tmpn, e2nw2, e2nb2, e2nm, N_, D_, D_, 1);

    // ---- node GRU loop ×3 ----
    for (int it = 0; it < 3; ++it) {
        (void)hipMemsetAsync(n2n, 0, N_ * D_ * 4, stream);
        k_scatter_n2n<<<dim3(E_, 2), 256, 0, stream>>>(rp, rep, ns, n2n);
        k_scale_rows<<<(N_ * D_ + 255) / 256, 256, 0, stream>>>(n2n, inv_deg);
        gemm_nt<<<ggrid(N_, D_), 256, 0, stream>>>(n2n, n2nw1, n2nb1, tmpn, N_, D_, D_, 1);
        gemm_nt<<<ggrid(N_, D_), 256, 0, stream>>>(tmpn, n2nw2, n2nb2, n2nm, N_, D_, D_, 1);
        k_combine<<<(N_ * D_ + 255) / 256, 256, 0, stream>>>(n2nm, e2nm, xin);
        gemm_nt<<<ggrid(N_, 3 * D_), 256, 0, stream>>>(xin, ngwih, nullptr, gin, N_, 3 * D_, D_, 0);
        gemm_nt<<<ggrid(N_, 3 * D_), 256, 0, stream>>>(ns, ngwhh, nullptr, ghn, N_, 3 * D_, D_, 0);
        k_gru<<<(N_ * D_ + 255) / 256, 256, 0, stream>>>(gin, ghn, ngbih, ngbhh, ns, N_);
    }

    // ---- obj_dists ----
    k_obj_dists<<<(N_ * NOBJ_ + 255) / 256, 256, 0, stream>>>(lab, out_obj);

    // ---- node_states2 = [x|ns|emb2] @ nw2^T + nb2 ----
    k_build_A2<<<((size_t)N_ * K2_ + 255) / 256, 256, 0, stream>>>(x, lab, emb2, ns, Abig);
    gemm_nt<<<ggrid(N_, D_), 256, 0, stream>>>(Abig, nw2, nb2, ns, N_, D_, K2_, 0);

    // ---- edge GRU loop: msg and gi are loop-invariant ----
    k_build_ek<<<((size_t)E_ * 2 * D_ + 255) / 256, 256, 0, stream>>>(rp, ns, Abig);
    gemm_nt<<<ggrid(E_, D_), 256, 0, stream>>>(Abig, n2ew1, n2eb1, erep, E_, D_, 2 * D_, 1);
    gemm_nt<<<ggrid(E_, D_), 256, 0, stream>>>(erep, n2ew2, n2eb2, msg, E_, D_, D_, 1);
    gemm_nt<<<ggrid(E_, 3 * D_), 256, 0, stream>>>(msg, egwih, nullptr, gie, E_, 3 * D_, D_, 0);
    for (int it = 0; it < 3; ++it) {
        gemm_nt<<<ggrid(E_, 3 * D_), 256, 0, stream>>>(es, egwhh, nullptr, ghe, E_, 3 * D_, D_, 0);
        k_gru<<<(E_ * D_ + 255) / 256, 256, 0, stream>>>(gie, ghe, nullptr, nullptr, es, E_);
    }

    // ---- rel_dists ----
    gemm_nt<<<ggrid(E_, NREL_), 256, 0, stream>>>(es, relw, relb, out_rel, E_, NREL_, D_, 0);
}

// Round 4
// 1006.763 us; speedup vs baseline: 5.0807x; 5.0807x over previous
//
#include <hip/hip_runtime.h>

typedef unsigned short ushort_t;
typedef unsigned int uint_t;

#define N_    384
#define E_    3072
#define CIN_  4096
#define EMB_  200
#define D_    512
#define NOBJ_ 151
#define NREL_ 51
#define K1_   (CIN_ + EMB_ + 128)   // 4424
#define K1P_  4448                  // pad to %32
#define K2_   (CIN_ + EMB_ + D_)    // 4808
#define K2P_  4832

__device__ __forceinline__ ushort_t f2b(float f) {
    uint_t u = __float_as_uint(f);
    u += 0x7FFFu + ((u >> 16) & 1u);           // RNE
    return (ushort_t)(u >> 16);
}

// ---------------- pair dedup ----------------
__global__ void k_pair_min(const int* __restrict__ rp, int* __restrict__ mapMin) {
    int e = blockIdx.x * blockDim.x + threadIdx.x;
    if (e >= E_) return;
    atomicMin(&mapMin[rp[2 * e] * N_ + rp[2 * e + 1]], e);
}
__global__ void k_pair_rep(const int* __restrict__ rp, const int* __restrict__ mapMin,
                           int* __restrict__ rep, int* __restrict__ deg_cnt) {
    int e = blockIdx.x * blockDim.x + threadIdx.x;
    if (e >= E_) return;
    int r = mapMin[rp[2 * e] * N_ + rp[2 * e + 1]];
    rep[e] = r;
    if (r == e) atomicAdd(&deg_cnt[rp[2 * e]], 1);
}
__global__ void k_inv_deg(const int* __restrict__ deg_cnt, float* __restrict__ inv_deg) {
    int i = blockIdx.x * blockDim.x + threadIdx.x;
    if (i < N_) inv_deg[i] = 1.0f / ((float)deg_cnt[i] + 1e-6f);
}

// ---------------- pos MLP + batchnorm ----------------
__global__ void k_pos1(const float* __restrict__ pi, const float* __restrict__ w,
                       const float* __restrict__ b, float* __restrict__ ph) {
    int idx = blockIdx.x * blockDim.x + threadIdx.x;
    if (idx >= N_ * 32) return;
    int i = idx / 32, f = idx % 32;
    float s = b[f];
    for (int k = 0; k < 9; ++k) s += pi[i * 9 + k] * w[f * 9 + k];
    ph[idx] = s;
}
__global__ void k_pos_stats(const float* __restrict__ ph, float* __restrict__ mu,
                            float* __restrict__ rstd) {
    int f = threadIdx.x;
    if (f >= 32) return;
    float s = 0.f;
    for (int i = 0; i < N_; ++i) s += ph[i * 32 + f];
    float m = s / N_;
    float v = 0.f;
    for (int i = 0; i < N_; ++i) { float d = ph[i * 32 + f] - m; v += d * d; }
    v /= N_;
    mu[f] = m;
    rstd[f] = rsqrtf(v + 1e-5f);
}
__global__ void k_pos_norm(const float* __restrict__ ph, const float* __restrict__ mu,
                           const float* __restrict__ rstd, const float* __restrict__ g,
                           const float* __restrict__ be, float* __restrict__ out) {
    int idx = blockIdx.x * blockDim.x + threadIdx.x;
    if (idx >= N_ * 32) return;
    int f = idx % 32;
    out[idx] = (ph[idx] - mu[f]) * rstd[f] * g[f] + be[f];
}
__global__ void k_pos2(const float* __restrict__ pn, const float* __restrict__ w,
                       const float* __restrict__ b, float* __restrict__ out) {
    int idx = blockIdx.x * blockDim.x + threadIdx.x;
    if (idx >= N_ * 128) return;
    int i = idx / 128, f = idx % 128;
    float s = b[f];
    for (int k = 0; k < 32; ++k) s += pn[i * 32 + k] * w[f * 32 + k];
    out[idx] = fmaxf(s, 0.f);
}

// ---------------- bf16 concat builders (zero-padded K) ----------------
__global__ void k_build_A1b(const float* __restrict__ x, const int* __restrict__ lab,
                            const float* __restrict__ emb1, const float* __restrict__ pe,
                            ushort_t* __restrict__ A) {
    int idx = blockIdx.x * blockDim.x + threadIdx.x;
    if (idx >= N_ * K1P_) return;
    int i = idx / K1P_, c = idx % K1P_;
    float v = 0.f;
    if (c < CIN_)             v = x[(size_t)i * CIN_ + c];
    else if (c < CIN_ + EMB_) v = emb1[lab[i] * EMB_ + (c - CIN_)];
    else if (c < K1_)         v = pe[i * 128 + (c - CIN_ - EMB_)];
    A[idx] = f2b(v);
}
__global__ void k_build_A2b(const float* __restrict__ x, const int* __restrict__ lab,
                            const float* __restrict__ emb2, const float* __restrict__ ns,
                            ushort_t* __restrict__ A) {
    int idx = blockIdx.x * blockDim.x + threadIdx.x;
    if (idx >= N_ * K2P_) return;
    int i = idx / K2P_, c = idx % K2P_;
    float v = 0.f;
    if (c < CIN_)             v = x[(size_t)i * CIN_ + c];
    else if (c < CIN_ + D_)   v = ns[i * D_ + (c - CIN_)];
    else if (c < K2_)         v = emb2[lab[i] * EMB_ + (c - CIN_ - D_)];
    A[idx] = f2b(v);
}
__global__ void k_build_ekb(const int* __restrict__ rp, const float* __restrict__ ns,
                            ushort_t* __restrict__ ek) {
    int idx = blockIdx.x * blockDim.x + threadIdx.x;
    if (idx >= E_ * 2 * D_) return;
    int e = idx / (2 * D_), c = idx % (2 * D_);
    float v = (c < D_) ? ns[rp[2 * e] * D_ + c] : ns[rp[2 * e + 1] * D_ + (c - D_)];
    ek[idx] = f2b(v);
}

// ---------------- batched f32 -> bf16 weight convert with K/row pad ----------------
struct ConvDesc { const float* src; ushort_t* dst; int K, Kp, rows, rowsp; };
struct ConvArgs { ConvDesc d[16]; };
__global__ void k_conv_batch(ConvArgs a) {
    ConvDesc c = a.d[blockIdx.y];
    size_t pairs = ((size_t)c.rowsp * c.Kp) >> 1;
    size_t stride = (size_t)gridDim.x * blockDim.x;
    for (size_t i = (size_t)blockIdx.x * blockDim.x + threadIdx.x; i < pairs; i += stride) {
        size_t e0 = i << 1;
        int row = (int)(e0 / c.Kp), k = (int)(e0 % c.Kp);
        uint_t ov = 0;
        if (row < c.rows && k < c.K) {
            float2 v = *(const float2*)(c.src + (size_t)row * c.K + k);
            ov = (uint_t)f2b(v.x) | ((uint_t)f2b(v.y) << 16);
        }
        *(uint_t*)(c.dst + (size_t)row * c.Kp + k) = ov;
    }
}
__global__ void k_f2b_n(const float* __restrict__ s, ushort_t* __restrict__ d, int n) {
    int i = blockIdx.x * blockDim.x + threadIdx.x;
    if (i < n) d[i] = f2b(s[i]);
}

// ---------------- scatter / pointwise ----------------
__global__ void k_scatter_edge(const float* __restrict__ er, const int* __restrict__ rep,
                               float* __restrict__ es) {
    int e = blockIdx.x;
    int d = blockIdx.y * 256 + threadIdx.x;
    atomicAdd(&es[(size_t)rep[e] * D_ + d], er[(size_t)e * D_ + d]);
}
__global__ void k_broadcast_es(const int* __restrict__ rep, float* __restrict__ es,
                               ushort_t* __restrict__ esb) {
    int idx = blockIdx.x * blockDim.x + threadIdx.x;
    if (idx >= E_ * D_) return;
    int e = idx / D_, d = idx % D_;
    float v = es[(size_t)rep[e] * D_ + d];
    es[idx] = v;
    esb[idx] = f2b(v);
}
__global__ void k_scatter_e2n(const int* __restrict__ rp, const int* __restrict__ rep,
                              const float* __restrict__ es, float* __restrict__ e2n) {
    int e = blockIdx.x;
    if (rep[e] != e) return;
    int d = blockIdx.y * 256 + threadIdx.x;
    atomicAdd(&e2n[rp[2 * e + 1] * D_ + d], es[(size_t)e * D_ + d]);
}
__global__ void k_scatter_n2n(const int* __restrict__ rp, const int* __restrict__ rep,
                              const float* __restrict__ ns, float* __restrict__ n2n) {
    int e = blockIdx.x;
    if (rep[e] != e) return;
    int d = blockIdx.y * 256 + threadIdx.x;
    atomicAdd(&n2n[rp[2 * e] * D_ + d], ns[rp[2 * e + 1] * D_ + d]);
}
__global__ void k_scale_rows_b(const float* __restrict__ a, const float* __restrict__ inv_deg,
                               ushort_t* __restrict__ ob) {
    int idx = blockIdx.x * blockDim.x + threadIdx.x;
    if (idx >= N_ * D_) return;
    ob[idx] = f2b(a[idx] * inv_deg[idx / D_]);
}
__global__ void k_combine_b(const float* __restrict__ a, const float* __restrict__ b,
                            ushort_t* __restrict__ o) {
    int idx = blockIdx.x * blockDim.x + threadIdx.x;
    if (idx >= N_ * D_) return;
    o[idx] = f2b(0.5f * a[idx] + 0.5f * b[idx]);
}
__global__ void k_gru(const float* __restrict__ gi, const float* __restrict__ gh,
                      const float* __restrict__ bih, const float* __restrict__ bhh,
                      float* __restrict__ h, ushort_t* __restrict__ hb, int M) {
    int idx = blockIdx.x * blockDim.x + threadIdx.x;
    if (idx >= M * D_) return;
    int m = idx / D_, d = idx % D_;
    size_t b3 = (size_t)m * 3 * D_;
    float ir = gi[b3 + d], iz = gi[b3 + D_ + d], ig = gi[b3 + 2 * D_ + d];
    float hr = gh[b3 + d], hz = gh[b3 + D_ + d], hg = gh[b3 + 2 * D_ + d];
    if (bih) { ir += bih[d]; iz += bih[D_ + d]; ig += bih[2 * D_ + d]; }
    if (bhh) { hr += bhh[d]; hz += bhh[D_ + d]; hg += bhh[2 * D_ + d]; }
    float r = 1.f / (1.f + expf(-(ir + hr)));
    float z = 1.f / (1.f + expf(-(iz + hz)));
    float g = tanhf(ig + r * hg);
    size_t hi = (size_t)m * D_ + d;
    float nv = (1.f - z) * g + z * h[hi];
    h[hi] = nv;
    if (hb) hb[hi] = f2b(nv);
}
__global__ void k_obj_dists(const int* __restrict__ lab, float* __restrict__ out) {
    int idx = blockIdx.x * blockDim.x + threadIdx.x;
    if (idx >= N_ * NOBJ_) return;
    out[idx] = (idx % NOBJ_ == lab[idx / NOBJ_]) ? 1000.f : -1000.f;
}

// ---------------- bf16 MFMA GEMM: C[M,N] = A[M,K] @ B[N,K]^T ----------------
// A,B bf16 row-major; K % 32 == 0, rows of staged tiles must be in-bounds
// (M % (FM*32) == 0 and B buffer has >= ceil tiles rows); epilogue masks M/N.
typedef __attribute__((ext_vector_type(8))) short sh8;
typedef __attribute__((ext_vector_type(4))) float f32x4;

#define GLOAD_LDS16(gp, lp)                                                        \
    __builtin_amdgcn_global_load_lds((__attribute__((address_space(1))) void*)(gp),\
                                     (__attribute__((address_space(3))) void*)(lp),\
                                     16, 0, 0)

template <int FM, int FN>
__global__ __launch_bounds__(256) void gemm_mfma(const ushort_t* __restrict__ A,
                                                 const ushort_t* __restrict__ B,
                                                 const float* __restrict__ bias,
                                                 float* __restrict__ C,
                                                 ushort_t* __restrict__ Cb,
                                                 int M, int N, int K, int relu) {
    constexpr int BM = FM * 32, BN = FN * 32;
    constexpr int AISS = BM / 64, BISS = BN / 64;
    __shared__ ushort_t As[BM * 32];
    __shared__ ushort_t Bs[BN * 32];
    const int tid = threadIdx.x;
    const int lane = tid & 63, wid = tid >> 6;
    const int wr = wid >> 1, wc = wid & 1;
    const int bm = blockIdx.y * BM, bn = blockIdx.x * BN;
    const int ar = tid >> 2, ac = (tid & 3) * 8;   // staging: 4 thr/row, 8 elems each
    const int l15 = lane & 15, lg = lane >> 4;

    f32x4 acc[FM][FN];
#pragma unroll
    for (int m = 0; m < FM; ++m)
#pragma unroll
        for (int n = 0; n < FN; ++n) acc[m][n] = (f32x4){0.f, 0.f, 0.f, 0.f};

    for (int k0 = 0; k0 < K; k0 += 32) {
#pragma unroll
        for (int i = 0; i < AISS; ++i)
            GLOAD_LDS16(A + (size_t)(bm + i * 64 + ar) * K + k0 + ac,
                        &As[(i * 64 + ar) * 32 + ac]);
#pragma unroll
        for (int i = 0; i < BISS; ++i)
            GLOAD_LDS16(B + (size_t)(bn + i * 64 + ar) * K + k0 + ac,
                        &Bs[(i * 64 + ar) * 32 + ac]);
        __syncthreads();
        sh8 af[FM], bf[FN];
#pragma unroll
        for (int m = 0; m < FM; ++m)
            af[m] = *(const sh8*)&As[(wr * FM * 16 + m * 16 + l15) * 32 + lg * 8];
#pragma unroll
        for (int n = 0; n < FN; ++n)
            bf[n] = *(const sh8*)&Bs[(wc * FN * 16 + n * 16 + l15) * 32 + lg * 8];
#pragma unroll
        for (int m = 0; m < FM; ++m)
#pragma unroll
            for (int n = 0; n < FN; ++n)
                acc[m][n] = __builtin_amdgcn_mfma_f32_16x16x32_bf16(af[m], bf[n], acc[m][n], 0, 0, 0);
        __syncthreads();
    }

    const int r0 = bm + wr * FM * 16, c0 = bn + wc * FN * 16;
#pragma unroll
    for (int m = 0; m < FM; ++m)
#pragma unroll
        for (int n = 0; n < FN; ++n)
#pragma unroll
            for (int j = 0; j < 4; ++j) {
                int row = r0 + m * 16 + lg * 4 + j;
                int col = c0 + n * 16 + l15;
                if (row < M && col < N) {
                    float v = acc[m][n][j] + (bias ? bias[col] : 0.f);
                    if (relu) v = fmaxf(v, 0.f);
                    if (C)  C[(size_t)row * N + col] = v;
                    if (Cb) Cb[(size_t)row * N + col] = f2b(v);
                }
            }
}

static inline dim3 mgrid(int M, int N, int FM, int FN) {
    return dim3((N + FN * 32 - 1) / (FN * 32), (M + FM * 32 - 1) / (FM * 32));
}

extern "C" void kernel_launch(void* const* d_in, const int* in_sizes, int n_in,
                              void* d_out, int out_size, void* d_ws, size_t ws_size,
                              hipStream_t stream) {
    const float* x      = (const float*)d_in[0];
    const float* posi   = (const float*)d_in[1];
    const float* unionf = (const float*)d_in[2];
    const int*   lab    = (const int*)d_in[3];
    const int*   rp     = (const int*)d_in[4];
    const float* emb1   = (const float*)d_in[5];
    const float* emb2   = (const float*)d_in[6];
    const float* nw     = (const float*)d_in[7];
    const float* nb     = (const float*)d_in[8];
    const float* nw2    = (const float*)d_in[9];
    const float* nb2    = (const float*)d_in[10];
    const float* ew     = (const float*)d_in[11];
    const float* eb     = (const float*)d_in[12];
    const float* pw1    = (const float*)d_in[13];
    const float* pb1    = (const float*)d_in[14];
    const float* pg     = (const float*)d_in[15];
    const float* pbe    = (const float*)d_in[16];
    const float* pw2    = (const float*)d_in[17];
    const float* pb2    = (const float*)d_in[18];
    const float* ngwih  = (const float*)d_in[19];
    const float* ngwhh  = (const float*)d_in[20];
    const float* ngbih  = (const float*)d_in[21];
    const float* ngbhh  = (const float*)d_in[22];
    const float* egwih  = (const float*)d_in[23];
    const float* egwhh  = (const float*)d_in[24];
    const float* n2nw1  = (const float*)d_in[25];
    const float* n2nb1  = (const float*)d_in[26];
    const float* n2nw2  = (const float*)d_in[27];
    const float* n2nb2  = (const float*)d_in[28];
    const float* e2nw1  = (const float*)d_in[29];
    const float* e2nb1  = (const float*)d_in[30];
    const float* e2nw2  = (const float*)d_in[31];
    const float* e2nb2  = (const float*)d_in[32];
    const float* n2ew1  = (const float*)d_in[33];
    const float* n2eb1  = (const float*)d_in[34];
    const float* n2ew2  = (const float*)d_in[35];
    const float* n2eb2  = (const float*)d_in[36];
    const float* relw   = (const float*)d_in[37];
    const float* relb   = (const float*)d_in[38];

    size_t off = 0;
    auto alloc = [&](size_t bytes) {
        off = (off + 255) & ~(size_t)255;
        char* p = (char*)d_ws + off;
        off += bytes;
        return (void*)p;
    };
    int*      mapMin  = (int*)alloc((size_t)N_ * N_ * 4);
    int*      rep     = (int*)alloc(E_ * 4);
    int*      deg_cnt = (int*)alloc(N_ * 4);
    float*    inv_deg = (float*)alloc(N_ * 4);
    float*    ph      = (float*)alloc(N_ * 32 * 4);
    float*    mu      = (float*)alloc(32 * 4);
    float*    rstd    = (float*)alloc(32 * 4);
    float*    posn    = (float*)alloc(N_ * 32 * 4);
    float*    pe      = (float*)alloc(N_ * 128 * 4);
    float*    ns      = (float*)alloc((size_t)N_ * D_ * 4);
    ushort_t* nsb     = (ushort_t*)alloc((size_t)N_ * D_ * 2);
    // union: A1b (384x4448x2=3.42M) / A2b (3.71M) / ekb (6.29M) -- sequential lifetimes
    char*     unionU  = (char*)alloc((size_t)E_ * 2 * D_ * 2);
    ushort_t* A1b = (ushort_t*)unionU;
    ushort_t* A2b = (ushort_t*)unionU;
    ushort_t* ekb = (ushort_t*)unionU;
    // union: ufb bf16 (25.2M, early) / gie f32 (18.9M, late)
    char*     ufbU = (char*)alloc((size_t)E_ * CIN_ * 2);
    ushort_t* ufb = (ushort_t*)ufbU;
    float*    gie = (float*)ufbU;
    // union: erep f32 (6.29M, early) / erepb+msgb bf16 (3.15M+3.15M, late)
    char*     erepU = (char*)alloc((size_t)E_ * D_ * 4);
    float*    erep  = (float*)erepU;
    ushort_t* erepb = (ushort_t*)erepU;
    ushort_t* msgb  = (ushort_t*)(erepU + (size_t)E_ * D_ * 2);
    float*    es    = (float*)alloc((size_t)E_ * D_ * 4);
    ushort_t* esb   = (ushort_t*)alloc((size_t)E_ * D_ * 2);
    float*    e2n   = (float*)alloc((size_t)N_ * D_ * 4);
    ushort_t* e2nb  = (ushort_t*)alloc((size_t)N_ * D_ * 2);
    ushort_t* tmpb  = (ushort_t*)alloc((size_t)N_ * D_ * 2);
    float*    e2nm  = (float*)alloc((size_t)N_ * D_ * 4);
    float*    n2n   = (float*)alloc((size_t)N_ * D_ * 4);
    ushort_t* n2nb  = (ushort_t*)alloc((size_t)N_ * D_ * 2);
    float*    n2nm  = (float*)alloc((size_t)N_ * D_ * 4);
    ushort_t* xinb  = (ushort_t*)alloc((size_t)N_ * D_ * 2);
    // union: ghe f32 (18.9M, edge loop) / gin+ghn f32 (2.36M each, node loop)
    char*     gheU = (char*)alloc((size_t)E_ * 3 * D_ * 4);
    float*    ghe = (float*)gheU;
    float*    gin = (float*)gheU;
    float*    ghn = (float*)(gheU + (size_t)N_ * 3 * D_ * 4);
    // bf16 weights
    ushort_t* nwb     = (ushort_t*)alloc((size_t)D_ * K1P_ * 2);
    ushort_t* nw2b    = (ushort_t*)alloc((size_t)D_ * K2P_ * 2);
    ushort_t* ewb     = (ushort_t*)alloc((size_t)D_ * CIN_ * 2);
    ushort_t* ngwihb  = (ushort_t*)alloc((size_t)3 * D_ * D_ * 2);
    ushort_t* ngwhhb  = (ushort_t*)alloc((size_t)3 * D_ * D_ * 2);
    ushort_t* egwihb  = (ushort_t*)alloc((size_t)3 * D_ * D_ * 2);
    ushort_t* egwhhb  = (ushort_t*)alloc((size_t)3 * D_ * D_ * 2);
    ushort_t* n2nw1b  = (ushort_t*)alloc((size_t)D_ * D_ * 2);
    ushort_t* n2nw2b  = (ushort_t*)alloc((size_t)D_ * D_ * 2);
    ushort_t* e2nw1b  = (ushort_t*)alloc((size_t)D_ * D_ * 2);
    ushort_t* e2nw2b  = (ushort_t*)alloc((size_t)D_ * D_ * 2);
    ushort_t* n2ew1b  = (ushort_t*)alloc((size_t)D_ * 2 * D_ * 2);
    ushort_t* n2ew2b  = (ushort_t*)alloc((size_t)D_ * D_ * 2);
    ushort_t* relwb   = (ushort_t*)alloc((size_t)64 * D_ * 2);
    if (off > ws_size) return;  // visible failure if workspace too small

    float* out_obj = (float*)d_out;
    float* out_rel = (float*)d_out + N_ * NOBJ_;

    // ---- weight + union_features bf16 conversion (one batched kernel) ----
    ConvArgs ca;
    int ci = 0;
    auto addc = [&](const float* s, ushort_t* dptr, int K, int Kp, int rows, int rowsp) {
        ca.d[ci++] = ConvDesc{s, dptr, K, Kp, rows, rowsp};
    };
    addc(nw,    nwb,    K1_,      K1P_,     D_,       D_);
    addc(nw2,   nw2b,   K2_,      K2P_,     D_,       D_);
    addc(ew,    ewb,    CIN_,     CIN_,     D_,       D_);
    addc(ngwih, ngwihb, D_,       D_,       3 * D_,   3 * D_);
    addc(ngwhh, ngwhhb, D_,       D_,       3 * D_,   3 * D_);
    addc(egwih, egwihb, D_,       D_,       3 * D_,   3 * D_);
    addc(egwhh, egwhhb, D_,       D_,       3 * D_,   3 * D_);
    addc(n2nw1, n2nw1b, D_,       D_,       D_,       D_);
    addc(n2nw2, n2nw2b, D_,       D_,       D_,       D_);
    addc(e2nw1, e2nw1b, D_,       D_,       D_,       D_);
    addc(e2nw2, e2nw2b, D_,       D_,       D_,       D_);
    addc(n2ew1, n2ew1b, 2 * D_,   2 * D_,   D_,       D_);
    addc(n2ew2, n2ew2b, D_,       D_,       D_,       D_);
    addc(relw,  relwb,  D_,       D_,       NREL_,    64);
    addc(unionf, ufb,   CIN_,     CIN_,     E_,       E_);
    for (; ci < 16;) ca.d[ci++] = ConvDesc{nullptr, nullptr, 0, 2, 0, 0};
    k_conv_batch<<<dim3(128, 15), 256, 0, stream>>>(ca);

    // ---- pair dedup + degrees ----
    (void)hipMemsetAsync(mapMin, 0x7F, (size_t)N_ * N_ * 4, stream);
    (void)hipMemsetAsync(deg_cnt, 0, N_ * 4, stream);
    k_pair_min<<<(E_ + 255) / 256, 256, 0, stream>>>(rp, mapMin);
    k_pair_rep<<<(E_ + 255) / 256, 256, 0, stream>>>(rp, mapMin, rep, deg_cnt);
    k_inv_deg<<<(N_ + 255) / 256, 256, 0, stream>>>(deg_cnt, inv_deg);

    // ---- pos embed ----
    k_pos1<<<(N_ * 32 + 255) / 256, 256, 0, stream>>>(posi, pw1, pb1, ph);
    k_pos_stats<<<1, 64, 0, stream>>>(ph, mu, rstd);
    k_pos_norm<<<(N_ * 32 + 255) / 256, 256, 0, stream>>>(ph, mu, rstd, pg, pbe, posn);
    k_pos2<<<(N_ * 128 + 255) / 256, 256, 0, stream>>>(posn, pw2, pb2, pe);

    // ---- node_states = [x|emb1|pos] @ nw^T + nb (dual-store bf16) ----
    k_build_A1b<<<((size_t)N_ * K1P_ + 255) / 256, 256, 0, stream>>>(x, lab, emb1, pe, A1b);
    gemm_mfma<2, 2><<<mgrid(N_, D_, 2, 2), 256, 0, stream>>>(A1b, nwb, nb, ns, nsb, N_, D_, K1P_, 0);

    // ---- edge_rep + sparse edge_states ----
    gemm_mfma<4, 4><<<mgrid(E_, D_, 4, 4), 256, 0, stream>>>(ufb, ewb, eb, erep, nullptr, E_, D_, CIN_, 0);
    (void)hipMemsetAsync(es, 0, (size_t)E_ * D_ * 4, stream);
    k_scatter_edge<<<dim3(E_, 2), 256, 0, stream>>>(erep, rep, es);
    k_broadcast_es<<<(E_ * D_ + 255) / 256, 256, 0, stream>>>(rep, es, esb);

    // ---- e2n (loop-invariant) ----
    (void)hipMemsetAsync(e2n, 0, (size_t)N_ * D_ * 4, stream);
    k_scatter_e2n<<<dim3(E_, 2), 256, 0, stream>>>(rp, rep, es, e2n);
    k_f2b_n<<<(N_ * D_ + 255) / 256, 256, 0, stream>>>(e2n, e2nb, N_ * D_);
    gemm_mfma<2, 2><<<mgrid(N_, D_, 2, 2), 256, 0, stream>>>(e2nb, e2nw1b, e2nb1, nullptr, tmpb, N_, D_, D_, 1);
    gemm_mfma<2, 2><<<mgrid(N_, D_, 2, 2), 256, 0, stream>>>(tmpb, e2nw2b, e2nb2, e2nm, nullptr, N_, D_, D_, 1);

    // ---- node GRU loop x3 ----
    for (int it = 0; it < 3; ++it) {
        (void)hipMemsetAsync(n2n, 0, (size_t)N_ * D_ * 4, stream);
        k_scatter_n2n<<<dim3(E_, 2), 256, 0, stream>>>(rp, rep, ns, n2n);
        k_scale_rows_b<<<(N_ * D_ + 255) / 256, 256, 0, stream>>>(n2n, inv_deg, n2nb);
        gemm_mfma<2, 2><<<mgrid(N_, D_, 2, 2), 256, 0, stream>>>(n2nb, n2nw1b, n2nb1, nullptr, tmpb, N_, D_, D_, 1);
        gemm_mfma<2, 2><<<mgrid(N_, D_, 2, 2), 256, 0, stream>>>(tmpb, n2nw2b, n2nb2, n2nm, nullptr, N_, D_, D_, 1);
        k_combine_b<<<(N_ * D_ + 255) / 256, 256, 0, stream>>>(n2nm, e2nm, xinb);
        gemm_mfma<2, 2><<<mgrid(N_, 3 * D_, 2, 2), 256, 0, stream>>>(xinb, ngwihb, nullptr, gin, nullptr, N_, 3 * D_, D_, 0);
        gemm_mfma<2, 2><<<mgrid(N_, 3 * D_, 2, 2), 256, 0, stream>>>(nsb, ngwhhb, nullptr, ghn, nullptr, N_, 3 * D_, D_, 0);
        k_gru<<<(N_ * D_ + 255) / 256, 256, 0, stream>>>(gin, ghn, ngbih, ngbhh, ns, nsb, N_);
    }

    // ---- obj_dists ----
    k_obj_dists<<<(N_ * NOBJ_ + 255) / 256, 256, 0, stream>>>(lab, out_obj);

    // ---- node_states2 ----
    k_build_A2b<<<((size_t)N_ * K2P_ + 255) / 256, 256, 0, stream>>>(x, lab, emb2, ns, A2b);
    gemm_mfma<2, 2><<<mgrid(N_, D_, 2, 2), 256, 0, stream>>>(A2b, nw2b, nb2, ns, nsb, N_, D_, K2P_, 0);

    // ---- edge loop: msg + gi loop-invariant ----
    k_build_ekb<<<((size_t)E_ * 2 * D_ + 255) / 256, 256, 0, stream>>>(rp, ns, ekb);
    gemm_mfma<4, 4><<<mgrid(E_, D_, 4, 4), 256, 0, stream>>>(ekb, n2ew1b, n2eb1, nullptr, erepb, E_, D_, 2 * D_, 1);
    gemm_mfma<4, 4><<<mgrid(E_, D_, 4, 4), 256, 0, stream>>>(erepb, n2ew2b, n2eb2, nullptr, msgb, E_, D_, D_, 1);
    gemm_mfma<4, 4><<<mgrid(E_, 3 * D_, 4, 4), 256, 0, stream>>>(msgb, egwihb, nullptr, gie, nullptr, E_, 3 * D_, D_, 0);
    for (int it = 0; it < 3; ++it) {
        gemm_mfma<4, 4><<<mgrid(E_, 3 * D_, 4, 4), 256, 0, stream>>>(esb, egwhhb, nullptr, ghe, nullptr, E_, 3 * D_, D_, 0);
        k_gru<<<(E_ * D_ + 255) / 256, 256, 0, stream>>>(gie, ghe, nullptr, nullptr, es, esb, E_);
    }

    // ---- rel_dists (N=51 masked, relwb zero-padded to 64 rows) ----
    gemm_mfma<2, 2><<<mgrid(E_, NREL_, 2, 2), 256, 0, stream>>>(esb, relwb, relb, out_rel, nullptr, E_, NREL_, D_, 0);
}

// Round 5
// 728.009 us; speedup vs baseline: 7.0261x; 1.3829x over previous
//
#include <hip/hip_runtime.h>

typedef unsigned short ushort_t;
typedef unsigned int uint_t;

#define N_    384
#define E_    3072
#define CIN_  4096
#define EMB_  200
#define D_    512
#define NOBJ_ 151
#define NREL_ 51
#define K1_   (CIN_ + EMB_ + 128)   // 4424
#define K1P_  4448                  // pad to %32
#define K2_   (CIN_ + EMB_ + D_)    // 4808
#define K2P_  4832

__device__ __forceinline__ ushort_t f2b(float f) {
    uint_t u = __float_as_uint(f);
    u += 0x7FFFu + ((u >> 16) & 1u);           // RNE
    return (ushort_t)(u >> 16);
}

// ---------------- pair dedup ----------------
__global__ void k_pair_min(const int* __restrict__ rp, int* __restrict__ mapMin) {
    int e = blockIdx.x * blockDim.x + threadIdx.x;
    if (e >= E_) return;
    atomicMin(&mapMin[rp[2 * e] * N_ + rp[2 * e + 1]], e);
}
__global__ void k_pair_rep(const int* __restrict__ rp, const int* __restrict__ mapMin,
                           int* __restrict__ rep, int* __restrict__ deg_cnt) {
    int e = blockIdx.x * blockDim.x + threadIdx.x;
    if (e >= E_) return;
    int r = mapMin[rp[2 * e] * N_ + rp[2 * e + 1]];
    rep[e] = r;
    if (r == e) atomicAdd(&deg_cnt[rp[2 * e]], 1);
}
__global__ void k_inv_deg(const int* __restrict__ deg_cnt, float* __restrict__ inv_deg) {
    int i = blockIdx.x * blockDim.x + threadIdx.x;
    if (i < N_) inv_deg[i] = 1.0f / ((float)deg_cnt[i] + 1e-6f);
}

// ---------------- fused pos MLP + batchnorm (1 block) + pos2 ----------------
__global__ __launch_bounds__(1024) void k_pos_a(const float* __restrict__ pi,
                                                const float* __restrict__ w1,
                                                const float* __restrict__ b1,
                                                const float* __restrict__ g,
                                                const float* __restrict__ be,
                                                float* __restrict__ posn) {
    __shared__ float ph[N_ * 32];
    __shared__ float mu_s[32], rs_s[32];
    int tid = threadIdx.x;
    for (int idx = tid; idx < N_ * 32; idx += 1024) {
        int i = idx >> 5, f = idx & 31;
        float s = b1[f];
        for (int k = 0; k < 9; ++k) s += pi[i * 9 + k] * w1[f * 9 + k];
        ph[idx] = s;
    }
    __syncthreads();
    if (tid < 32) {
        float s = 0.f;
        for (int i = 0; i < N_; ++i) s += ph[i * 32 + tid];
        float m = s / N_;
        float v = 0.f;
        for (int i = 0; i < N_; ++i) { float d = ph[i * 32 + tid] - m; v += d * d; }
        mu_s[tid] = m;
        rs_s[tid] = rsqrtf(v / N_ + 1e-5f);
    }
    __syncthreads();
    for (int idx = tid; idx < N_ * 32; idx += 1024) {
        int f = idx & 31;
        posn[idx] = (ph[idx] - mu_s[f]) * rs_s[f] * g[f] + be[f];
    }
}
__global__ void k_pos2(const float* __restrict__ pn, const float* __restrict__ w,
                       const float* __restrict__ b, float* __restrict__ out) {
    int idx = blockIdx.x * blockDim.x + threadIdx.x;
    if (idx >= N_ * 128) return;
    int i = idx / 128, f = idx % 128;
    float s = b[f];
    for (int k = 0; k < 32; ++k) s += pn[i * 32 + k] * w[f * 32 + k];
    out[idx] = fmaxf(s, 0.f);
}

// ---------------- bf16 concat builders (zero-padded K) ----------------
__global__ void k_build_A1b(const float* __restrict__ x, const int* __restrict__ lab,
                            const float* __restrict__ emb1, const float* __restrict__ pe,
                            ushort_t* __restrict__ A) {
    int idx = blockIdx.x * blockDim.x + threadIdx.x;
    if (idx >= N_ * K1P_) return;
    int i = idx / K1P_, c = idx % K1P_;
    float v = 0.f;
    if (c < CIN_)             v = x[(size_t)i * CIN_ + c];
    else if (c < CIN_ + EMB_) v = emb1[lab[i] * EMB_ + (c - CIN_)];
    else if (c < K1_)         v = pe[i * 128 + (c - CIN_ - EMB_)];
    A[idx] = f2b(v);
}
__global__ void k_build_A2b(const float* __restrict__ x, const int* __restrict__ lab,
                            const float* __restrict__ emb2, const float* __restrict__ ns,
                            ushort_t* __restrict__ A) {
    int idx = blockIdx.x * blockDim.x + threadIdx.x;
    if (idx >= N_ * K2P_) return;
    int i = idx / K2P_, c = idx % K2P_;
    float v = 0.f;
    if (c < CIN_)             v = x[(size_t)i * CIN_ + c];
    else if (c < CIN_ + D_)   v = ns[i * D_ + (c - CIN_)];
    else if (c < K2_)         v = emb2[lab[i] * EMB_ + (c - CIN_ - D_)];
    A[idx] = f2b(v);
}
__global__ void k_build_ekb(const int* __restrict__ rp, const float* __restrict__ ns,
                            ushort_t* __restrict__ ek) {
    int idx = blockIdx.x * blockDim.x + threadIdx.x;
    if (idx >= E_ * 2 * D_) return;
    int e = idx / (2 * D_), c = idx % (2 * D_);
    float v = (c < D_) ? ns[rp[2 * e] * D_ + c] : ns[rp[2 * e + 1] * D_ + (c - D_)];
    ek[idx] = f2b(v);
}

// ---------------- batched f32 -> bf16 convert: row-loop, float4, no division ----------------
struct ConvDesc { const float* src; ushort_t* dst; int K, Kp, rows, rowsp; };
struct ConvArgs { ConvDesc d[16]; };
__global__ void k_conv_batch(ConvArgs a) {
    ConvDesc c = a.d[blockIdx.y];
    for (int row = blockIdx.x; row < c.rowsp; row += gridDim.x) {
        const float* src = c.src + (size_t)row * c.K;
        ushort_t* dst = c.dst + (size_t)row * c.Kp;
        bool inrow = row < c.rows;
        for (int k = threadIdx.x * 4; k < c.Kp; k += blockDim.x * 4) {
            uint2 ov = {0u, 0u};
            if (inrow && k < c.K) {                 // K,Kp both %4==0: no straddle
                float4 v = *(const float4*)(src + k);
                ov.x = (uint_t)f2b(v.x) | ((uint_t)f2b(v.y) << 16);
                ov.y = (uint_t)f2b(v.z) | ((uint_t)f2b(v.w) << 16);
            }
            *(uint2*)(dst + k) = ov;
        }
    }
}
__global__ void k_f2b_n(const float* __restrict__ s, ushort_t* __restrict__ d, int n) {
    int i = blockIdx.x * blockDim.x + threadIdx.x;
    if (i < n) d[i] = f2b(s[i]);
}

// ---------------- scatter / pointwise ----------------
__global__ void k_scatter_edge(const float* __restrict__ er, const int* __restrict__ rep,
                               float* __restrict__ es) {
    int e = blockIdx.x;
    int d = blockIdx.y * 256 + threadIdx.x;
    atomicAdd(&es[(size_t)rep[e] * D_ + d], er[(size_t)e * D_ + d]);
}
__global__ void k_broadcast_es(const int* __restrict__ rep, float* __restrict__ es,
                               ushort_t* __restrict__ esb) {
    int idx = blockIdx.x * blockDim.x + threadIdx.x;
    if (idx >= E_ * D_) return;
    int e = idx / D_, d = idx % D_;
    float v = es[(size_t)rep[e] * D_ + d];
    es[idx] = v;
    esb[idx] = f2b(v);
}
__global__ void k_scatter_e2n(const int* __restrict__ rp, const int* __restrict__ rep,
                              const float* __restrict__ es, float* __restrict__ e2n) {
    int e = blockIdx.x;
    if (rep[e] != e) return;
    int d = blockIdx.y * 256 + threadIdx.x;
    atomicAdd(&e2n[rp[2 * e + 1] * D_ + d], es[(size_t)e * D_ + d]);
}
__global__ void k_scatter_n2n(const int* __restrict__ rp, const int* __restrict__ rep,
                              const float* __restrict__ ns, float* __restrict__ n2n) {
    int e = blockIdx.x;
    if (rep[e] != e) return;
    int d = blockIdx.y * 256 + threadIdx.x;
    atomicAdd(&n2n[rp[2 * e] * D_ + d], ns[rp[2 * e + 1] * D_ + d]);
}
__global__ void k_scale_rows_b(const float* __restrict__ a, const float* __restrict__ inv_deg,
                               ushort_t* __restrict__ ob) {
    int idx = blockIdx.x * blockDim.x + threadIdx.x;
    if (idx >= N_ * D_) return;
    ob[idx] = f2b(a[idx] * inv_deg[idx / D_]);
}
__global__ void k_combine_b(const float* __restrict__ a, const float* __restrict__ b,
                            ushort_t* __restrict__ o) {
    int idx = blockIdx.x * blockDim.x + threadIdx.x;
    if (idx >= N_ * D_) return;
    o[idx] = f2b(0.5f * a[idx] + 0.5f * b[idx]);
}
__global__ void k_gru(const float* __restrict__ gi, const float* __restrict__ gh,
                      const float* __restrict__ bih, const float* __restrict__ bhh,
                      float* __restrict__ h, ushort_t* __restrict__ hb, int M) {
    int idx = blockIdx.x * blockDim.x + threadIdx.x;
    if (idx >= M * D_) return;
    int m = idx / D_, d = idx % D_;
    size_t b3 = (size_t)m * 3 * D_;
    float ir = gi[b3 + d], iz = gi[b3 + D_ + d], ig = gi[b3 + 2 * D_ + d];
    float hr = gh[b3 + d], hz = gh[b3 + D_ + d], hg = gh[b3 + 2 * D_ + d];
    if (bih) { ir += bih[d]; iz += bih[D_ + d]; ig += bih[2 * D_ + d]; }
    if (bhh) { hr += bhh[d]; hz += bhh[D_ + d]; hg += bhh[2 * D_ + d]; }
    float r = 1.f / (1.f + expf(-(ir + hr)));
    float z = 1.f / (1.f + expf(-(iz + hz)));
    float g = tanhf(ig + r * hg);
    size_t hi = (size_t)m * D_ + d;
    float nv = (1.f - z) * g + z * h[hi];
    h[hi] = nv;
    if (hb) hb[hi] = f2b(nv);
}
__global__ void k_obj_dists(const int* __restrict__ lab, float* __restrict__ out) {
    int idx = blockIdx.x * blockDim.x + threadIdx.x;
    if (idx >= N_ * NOBJ_) return;
    out[idx] = (idx % NOBJ_ == lab[idx / NOBJ_]) ? 1000.f : -1000.f;
}

// ---------------- bf16 MFMA GEMM: C[M,N] = A[M,K] @ B[N,K]^T ----------------
// A,B bf16 row-major; K % 32 == 0; M % 32 == 0; B buffer rows >= ceil(N/32)*32.
typedef __attribute__((ext_vector_type(8))) short sh8;
typedef __attribute__((ext_vector_type(4))) float f32x4;

#define GLOAD_LDS16(gp, lp)                                                        \
    __builtin_amdgcn_global_load_lds((__attribute__((address_space(1))) void*)(gp),\
                                     (__attribute__((address_space(3))) void*)(lp),\
                                     16, 0, 0)

template <int FM, int FN>
__device__ __forceinline__ void gemm_body(ushort_t* As, ushort_t* Bs,
                                          const ushort_t* __restrict__ A,
                                          const ushort_t* __restrict__ B,
                                          const float* __restrict__ bias,
                                          float* __restrict__ C,
                                          ushort_t* __restrict__ Cb,
                                          int M, int N, int K, int relu,
                                          int bx, int by) {
    constexpr int BM = FM * 32, BN = FN * 32;
    constexpr int ATILES = (BM + 63) / 64, BTILES = (BN + 63) / 64;
    const int tid = threadIdx.x;
    const int lane = tid & 63, wid = tid >> 6;
    const int wr = wid >> 1, wc = wid & 1;
    const int bm = by * BM, bn = bx * BN;
    const int ar = tid >> 2, ac = (tid & 3) * 8;   // staging: 4 thr/row, 8 elems each
    const int l15 = lane & 15, lg = lane >> 4;

    f32x4 acc[FM][FN];
#pragma unroll
    for (int m = 0; m < FM; ++m)
#pragma unroll
        for (int n = 0; n < FN; ++n) acc[m][n] = (f32x4){0.f, 0.f, 0.f, 0.f};

    for (int k0 = 0; k0 < K; k0 += 32) {
#pragma unroll
        for (int i = 0; i < ATILES; ++i) {
            int r = i * 64 + ar;
            if ((BM & 63) == 0 || r < BM)          // wave-uniform predicate
                GLOAD_LDS16(A + (size_t)(bm + r) * K + k0 + ac, &As[r * 32 + ac]);
        }
#pragma unroll
        for (int i = 0; i < BTILES; ++i) {
            int r = i * 64 + ar;
            if ((BN & 63) == 0 || r < BN)
                GLOAD_LDS16(B + (size_t)(bn + r) * K + k0 + ac, &Bs[r * 32 + ac]);
        }
        __syncthreads();
        sh8 af[FM], bf[FN];
#pragma unroll
        for (int m = 0; m < FM; ++m)
            af[m] = *(const sh8*)&As[(wr * FM * 16 + m * 16 + l15) * 32 + lg * 8];
#pragma unroll
        for (int n = 0; n < FN; ++n)
            bf[n] = *(const sh8*)&Bs[(wc * FN * 16 + n * 16 + l15) * 32 + lg * 8];
#pragma unroll
        for (int m = 0; m < FM; ++m)
#pragma unroll
            for (int n = 0; n < FN; ++n)
                acc[m][n] = __builtin_amdgcn_mfma_f32_16x16x32_bf16(af[m], bf[n], acc[m][n], 0, 0, 0);
        __syncthreads();
    }

    const int r0 = bm + wr * FM * 16, c0 = bn + wc * FN * 16;
#pragma unroll
    for (int m = 0; m < FM; ++m)
#pragma unroll
        for (int n = 0; n < FN; ++n)
#pragma unroll
            for (int j = 0; j < 4; ++j) {
                int row = r0 + m * 16 + lg * 4 + j;
                int col = c0 + n * 16 + l15;
                if (row < M && col < N) {
                    float v = acc[m][n][j] + (bias ? bias[col] : 0.f);
                    if (relu) v = fmaxf(v, 0.f);
                    if (C)  C[(size_t)row * N + col] = v;
                    if (Cb) Cb[(size_t)row * N + col] = f2b(v);
                }
            }
}

template <int FM, int FN>
__global__ __launch_bounds__(256) void gemm_mfma(const ushort_t* __restrict__ A,
                                                 const ushort_t* __restrict__ B,
                                                 const float* __restrict__ bias,
                                                 float* __restrict__ C,
                                                 ushort_t* __restrict__ Cb,
                                                 int M, int N, int K, int relu) {
    __shared__ ushort_t As[FM * 32 * 32];
    __shared__ ushort_t Bs[FN * 32 * 32];
    gemm_body<FM, FN>(As, Bs, A, B, bias, C, Cb, M, N, K, relu, blockIdx.x, blockIdx.y);
}

// dual 32x32-tile GEMM: z=0 -> A0@B0->C0, z=1 -> A1@B1->C1 (no bias/relu, f32 out)
__global__ __launch_bounds__(256) void gemm_dual11(const ushort_t* __restrict__ A0,
                                                   const ushort_t* __restrict__ B0,
                                                   float* __restrict__ C0,
                                                   const ushort_t* __restrict__ A1,
                                                   const ushort_t* __restrict__ B1,
                                                   float* __restrict__ C1,
                                                   int M, int N, int K) {
    __shared__ ushort_t As[32 * 32];
    __shared__ ushort_t Bs[32 * 32];
    if (blockIdx.z == 0)
        gemm_body<1, 1>(As, Bs, A0, B0, nullptr, C0, nullptr, M, N, K, 0, blockIdx.x, blockIdx.y);
    else
        gemm_body<1, 1>(As, Bs, A1, B1, nullptr, C1, nullptr, M, N, K, 0, blockIdx.x, blockIdx.y);
}

static inline dim3 mgrid(int M, int N, int FM, int FN) {
    return dim3((N + FN * 32 - 1) / (FN * 32), (M + FM * 32 - 1) / (FM * 32));
}

extern "C" void kernel_launch(void* const* d_in, const int* in_sizes, int n_in,
                              void* d_out, int out_size, void* d_ws, size_t ws_size,
                              hipStream_t stream) {
    const float* x      = (const float*)d_in[0];
    const float* posi   = (const float*)d_in[1];
    const float* unionf = (const float*)d_in[2];
    const int*   lab    = (const int*)d_in[3];
    const int*   rp     = (const int*)d_in[4];
    const float* emb1   = (const float*)d_in[5];
    const float* emb2   = (const float*)d_in[6];
    const float* nw     = (const float*)d_in[7];
    const float* nb     = (const float*)d_in[8];
    const float* nw2    = (const float*)d_in[9];
    const float* nb2    = (const float*)d_in[10];
    const float* ew     = (const float*)d_in[11];
    const float* eb     = (const float*)d_in[12];
    const float* pw1    = (const float*)d_in[13];
    const float* pb1    = (const float*)d_in[14];
    const float* pg     = (const float*)d_in[15];
    const float* pbe    = (const float*)d_in[16];
    const float* pw2    = (const float*)d_in[17];
    const float* pb2    = (const float*)d_in[18];
    const float* ngwih  = (const float*)d_in[19];
    const float* ngwhh  = (const float*)d_in[20];
    const float* ngbih  = (const float*)d_in[21];
    const float* ngbhh  = (const float*)d_in[22];
    const float* egwih  = (const float*)d_in[23];
    const float* egwhh  = (const float*)d_in[24];
    const float* n2nw1  = (const float*)d_in[25];
    const float* n2nb1  = (const float*)d_in[26];
    const float* n2nw2  = (const float*)d_in[27];
    const float* n2nb2  = (const float*)d_in[28];
    const float* e2nw1  = (const float*)d_in[29];
    const float* e2nb1  = (const float*)d_in[30];
    const float* e2nw2  = (const float*)d_in[31];
    const float* e2nb2  = (const float*)d_in[32];
    const float* n2ew1  = (const float*)d_in[33];
    const float* n2eb1  = (const float*)d_in[34];
    const float* n2ew2  = (const float*)d_in[35];
    const float* n2eb2  = (const float*)d_in[36];
    const float* relw   = (const float*)d_in[37];
    const float* relb   = (const float*)d_in[38];

    size_t off = 0;
    auto alloc = [&](size_t bytes) {
        off = (off + 255) & ~(size_t)255;
        char* p = (char*)d_ws + off;
        off += bytes;
        return (void*)p;
    };
    int*      mapMin  = (int*)alloc((size_t)N_ * N_ * 4);
    int*      rep     = (int*)alloc(E_ * 4);
    int*      deg_cnt = (int*)alloc(N_ * 4);
    float*    inv_deg = (float*)alloc(N_ * 4);
    float*    posn    = (float*)alloc(N_ * 32 * 4);
    float*    pe      = (float*)alloc(N_ * 128 * 4);
    float*    ns      = (float*)alloc((size_t)N_ * D_ * 4);
    ushort_t* nsb     = (ushort_t*)alloc((size_t)N_ * D_ * 2);
    // union: A1b / A2b / ekb -- sequential lifetimes
    char*     unionU  = (char*)alloc((size_t)E_ * 2 * D_ * 2);
    ushort_t* A1b = (ushort_t*)unionU;
    ushort_t* A2b = (ushort_t*)unionU;
    ushort_t* ekb = (ushort_t*)unionU;
    // union: ufb bf16 (early) / gie f32 (late)
    char*     ufbU = (char*)alloc((size_t)E_ * CIN_ * 2);
    ushort_t* ufb = (ushort_t*)ufbU;
    float*    gie = (float*)ufbU;
    // union: erep f32 (early) / erepb+msgb bf16 (late)
    char*     erepU = (char*)alloc((size_t)E_ * D_ * 4);
    float*    erep  = (float*)erepU;
    ushort_t* erepb = (ushort_t*)erepU;
    ushort_t* msgb  = (ushort_t*)(erepU + (size_t)E_ * D_ * 2);
    float*    es    = (float*)alloc((size_t)E_ * D_ * 4);
    ushort_t* esb   = (ushort_t*)alloc((size_t)E_ * D_ * 2);
    float*    e2n   = (float*)alloc((size_t)N_ * D_ * 4);
    ushort_t* e2nb  = (ushort_t*)alloc((size_t)N_ * D_ * 2);
    ushort_t* tmpb  = (ushort_t*)alloc((size_t)N_ * D_ * 2);
    float*    e2nm  = (float*)alloc((size_t)N_ * D_ * 4);
    float*    n2n   = (float*)alloc((size_t)N_ * D_ * 4);
    ushort_t* n2nb  = (ushort_t*)alloc((size_t)N_ * D_ * 2);
    float*    n2nm  = (float*)alloc((size_t)N_ * D_ * 4);
    ushort_t* xinb  = (ushort_t*)alloc((size_t)N_ * D_ * 2);
    // union: ghe f32 (edge loop) / gin+ghn f32 (node loop)
    char*     gheU = (char*)alloc((size_t)E_ * 3 * D_ * 4);
    float*    ghe = (float*)gheU;
    float*    gin = (float*)gheU;
    float*    ghn = (float*)(gheU + (size_t)N_ * 3 * D_ * 4);
    // bf16 weights
    ushort_t* nwb     = (ushort_t*)alloc((size_t)D_ * K1P_ * 2);
    ushort_t* nw2b    = (ushort_t*)alloc((size_t)D_ * K2P_ * 2);
    ushort_t* ewb     = (ushort_t*)alloc((size_t)D_ * CIN_ * 2);
    ushort_t* ngwihb  = (ushort_t*)alloc((size_t)3 * D_ * D_ * 2);
    ushort_t* ngwhhb  = (ushort_t*)alloc((size_t)3 * D_ * D_ * 2);
    ushort_t* egwihb  = (ushort_t*)alloc((size_t)3 * D_ * D_ * 2);
    ushort_t* egwhhb  = (ushort_t*)alloc((size_t)3 * D_ * D_ * 2);
    ushort_t* n2nw1b  = (ushort_t*)alloc((size_t)D_ * D_ * 2);
    ushort_t* n2nw2b  = (ushort_t*)alloc((size_t)D_ * D_ * 2);
    ushort_t* e2nw1b  = (ushort_t*)alloc((size_t)D_ * D_ * 2);
    ushort_t* e2nw2b  = (ushort_t*)alloc((size_t)D_ * D_ * 2);
    ushort_t* n2ew1b  = (ushort_t*)alloc((size_t)D_ * 2 * D_ * 2);
    ushort_t* n2ew2b  = (ushort_t*)alloc((size_t)D_ * D_ * 2);
    ushort_t* relwb   = (ushort_t*)alloc((size_t)64 * D_ * 2);
    if (off > ws_size) return;  // visible failure if workspace too small

    float* out_obj = (float*)d_out;
    float* out_rel = (float*)d_out + N_ * NOBJ_;

    // ---- weight + union_features bf16 conversion (batched, row-loop, float4) ----
    ConvArgs ca;
    int ci = 0;
    auto addc = [&](const float* s, ushort_t* dptr, int K, int Kp, int rows, int rowsp) {
        ca.d[ci++] = ConvDesc{s, dptr, K, Kp, rows, rowsp};
    };
    addc(nw,    nwb,    K1_,      K1P_,     D_,       D_);
    addc(nw2,   nw2b,   K2_,      K2P_,     D_,       D_);
    addc(ew,    ewb,    CIN_,     CIN_,     D_,       D_);
    addc(ngwih, ngwihb, D_,       D_,       3 * D_,   3 * D_);
    addc(ngwhh, ngwhhb, D_,       D_,       3 * D_,   3 * D_);
    addc(egwih, egwihb, D_,       D_,       3 * D_,   3 * D_);
    addc(egwhh, egwhhb, D_,       D_,       3 * D_,   3 * D_);
    addc(n2nw1, n2nw1b, D_,       D_,       D_,       D_);
    addc(n2nw2, n2nw2b, D_,       D_,       D_,       D_);
    addc(e2nw1, e2nw1b, D_,       D_,       D_,       D_);
    addc(e2nw2, e2nw2b, D_,       D_,       D_,       D_);
    addc(n2ew1, n2ew1b, 2 * D_,   2 * D_,   D_,       D_);
    addc(n2ew2, n2ew2b, D_,       D_,       D_,       D_);
    addc(relw,  relwb,  D_,       D_,       NREL_,    64);
    addc(unionf, ufb,   CIN_,     CIN_,     E_,       E_);
    for (; ci < 16;) ca.d[ci++] = ConvDesc{nullptr, nullptr, 4, 4, 0, 0};
    k_conv_batch<<<dim3(512, 15), 256, 0, stream>>>(ca);

    // ---- pair dedup + degrees ----
    (void)hipMemsetAsync(mapMin, 0x7F, (size_t)N_ * N_ * 4, stream);
    (void)hipMemsetAsync(deg_cnt, 0, N_ * 4, stream);
    k_pair_min<<<(E_ + 255) / 256, 256, 0, stream>>>(rp, mapMin);
    k_pair_rep<<<(E_ + 255) / 256, 256, 0, stream>>>(rp, mapMin, rep, deg_cnt);
    k_inv_deg<<<(N_ + 255) / 256, 256, 0, stream>>>(deg_cnt, inv_deg);

    // ---- pos embed (fused BN) ----
    k_pos_a<<<1, 1024, 0, stream>>>(posi, pw1, pb1, pg, pbe, posn);
    k_pos2<<<(N_ * 128 + 255) / 256, 256, 0, stream>>>(posn, pw2, pb2, pe);

    // ---- node_states = [x|emb1|pos] @ nw^T + nb (dual-store bf16) ----
    k_build_A1b<<<((size_t)N_ * K1P_ + 255) / 256, 256, 0, stream>>>(x, lab, emb1, pe, A1b);
    gemm_mfma<1, 1><<<mgrid(N_, D_, 1, 1), 256, 0, stream>>>(A1b, nwb, nb, ns, nsb, N_, D_, K1P_, 0);

    // ---- edge_rep + sparse edge_states ----
    gemm_mfma<2, 2><<<mgrid(E_, D_, 2, 2), 256, 0, stream>>>(ufb, ewb, eb, erep, nullptr, E_, D_, CIN_, 0);
    (void)hipMemsetAsync(es, 0, (size_t)E_ * D_ * 4, stream);
    k_scatter_edge<<<dim3(E_, 2), 256, 0, stream>>>(erep, rep, es);
    k_broadcast_es<<<(E_ * D_ + 255) / 256, 256, 0, stream>>>(rep, es, esb);

    // ---- e2n (loop-invariant) ----
    (void)hipMemsetAsync(e2n, 0, (size_t)N_ * D_ * 4, stream);
    k_scatter_e2n<<<dim3(E_, 2), 256, 0, stream>>>(rp, rep, es, e2n);
    k_f2b_n<<<(N_ * D_ + 255) / 256, 256, 0, stream>>>(e2n, e2nb, N_ * D_);
    gemm_mfma<1, 1><<<mgrid(N_, D_, 1, 1), 256, 0, stream>>>(e2nb, e2nw1b, e2nb1, nullptr, tmpb, N_, D_, D_, 1);
    gemm_mfma<1, 1><<<mgrid(N_, D_, 1, 1), 256, 0, stream>>>(tmpb, e2nw2b, e2nb2, e2nm, nullptr, N_, D_, D_, 1);

    // ---- node GRU loop x3 ----
    for (int it = 0; it < 3; ++it) {
        (void)hipMemsetAsync(n2n, 0, (size_t)N_ * D_ * 4, stream);
        k_scatter_n2n<<<dim3(E_, 2), 256, 0, stream>>>(rp, rep, ns, n2n);
        k_scale_rows_b<<<(N_ * D_ + 255) / 256, 256, 0, stream>>>(n2n, inv_deg, n2nb);
        gemm_mfma<1, 1><<<mgrid(N_, D_, 1, 1), 256, 0, stream>>>(n2nb, n2nw1b, n2nb1, nullptr, tmpb, N_, D_, D_, 1);
        gemm_mfma<1, 1><<<mgrid(N_, D_, 1, 1), 256, 0, stream>>>(tmpb, n2nw2b, n2nb2, n2nm, nullptr, N_, D_, D_, 1);
        k_combine_b<<<(N_ * D_ + 255) / 256, 256, 0, stream>>>(n2nm, e2nm, xinb);
        {
            dim3 g = mgrid(N_, 3 * D_, 1, 1);
            gemm_dual11<<<dim3(g.x, g.y, 2), 256, 0, stream>>>(xinb, ngwihb, gin, nsb, ngwhhb, ghn, N_, 3 * D_, D_);
        }
        k_gru<<<(N_ * D_ + 255) / 256, 256, 0, stream>>>(gin, ghn, ngbih, ngbhh, ns, nsb, N_);
    }

    // ---- obj_dists ----
    k_obj_dists<<<(N_ * NOBJ_ + 255) / 256, 256, 0, stream>>>(lab, out_obj);

    // ---- node_states2 ----
    k_build_A2b<<<((size_t)N_ * K2P_ + 255) / 256, 256, 0, stream>>>(x, lab, emb2, ns, A2b);
    gemm_mfma<1, 1><<<mgrid(N_, D_, 1, 1), 256, 0, stream>>>(A2b, nw2b, nb2, ns, nsb, N_, D_, K2P_, 0);

    // ---- edge loop: msg + gi loop-invariant ----
    k_build_ekb<<<((size_t)E_ * 2 * D_ + 255) / 256, 256, 0, stream>>>(rp, ns, ekb);
    gemm_mfma<2, 2><<<mgrid(E_, D_, 2, 2), 256, 0, stream>>>(ekb, n2ew1b, n2eb1, nullptr, erepb, E_, D_, 2 * D_, 1);
    gemm_mfma<2, 2><<<mgrid(E_, D_, 2, 2), 256, 0, stream>>>(erepb, n2ew2b, n2eb2, nullptr, msgb, E_, D_, D_, 1);
    gemm_mfma<2, 4><<<mgrid(E_, 3 * D_, 2, 4), 256, 0, stream>>>(msgb, egwihb, nullptr, gie, nullptr, E_, 3 * D_, D_, 0);
    for (int it = 0; it < 3; ++it) {
        gemm_mfma<2, 4><<<mgrid(E_, 3 * D_, 2, 4), 256, 0, stream>>>(esb, egwhhb, nullptr, ghe, nullptr, E_, 3 * D_, D_, 0);
        k_gru<<<(E_ * D_ + 255) / 256, 256, 0, stream>>>(gie, ghe, nullptr, nullptr, es, esb, E_);
    }

    // ---- rel_dists (N=51 masked, relwb zero-padded to 64 rows) ----
    gemm_mfma<1, 1><<<mgrid(E_, NREL_, 1, 1), 256, 0, stream>>>(esb, relwb, relb, out_rel, nullptr, E_, NREL_, D_, 0);
}

// Round 6
// 705.046 us; speedup vs baseline: 7.2549x; 1.0326x over previous
//
#include <hip/hip_runtime.h>

typedef unsigned short ushort_t;
typedef unsigned int uint_t;

#define N_    384
#define E_    3072
#define CIN_  4096
#define EMB_  200
#define D_    512
#define NOBJ_ 151
#define NREL_ 51
#define K1_   (CIN_ + EMB_ + 128)   // 4424
#define K1P_  4448                  // pad to %32
#define K2_   (CIN_ + EMB_ + D_)    // 4808
#define K2P_  4832

__device__ __forceinline__ ushort_t f2b(float f) {
    uint_t u = __float_as_uint(f);
    u += 0x7FFFu + ((u >> 16) & 1u);           // RNE
    return (ushort_t)(u >> 16);
}

// ---------------- pair dedup ----------------
__global__ void k_pair_min(const int* __restrict__ rp, int* __restrict__ mapMin) {
    int e = blockIdx.x * blockDim.x + threadIdx.x;
    if (e >= E_) return;
    atomicMin(&mapMin[rp[2 * e] * N_ + rp[2 * e + 1]], e);
}
__global__ void k_pair_rep(const int* __restrict__ rp, const int* __restrict__ mapMin,
                           int* __restrict__ rep, int* __restrict__ deg_cnt) {
    int e = blockIdx.x * blockDim.x + threadIdx.x;
    if (e >= E_) return;
    int r = mapMin[rp[2 * e] * N_ + rp[2 * e + 1]];
    rep[e] = r;
    if (r == e) atomicAdd(&deg_cnt[rp[2 * e]], 1);
}
__global__ void k_inv_deg(const int* __restrict__ deg_cnt, float* __restrict__ inv_deg) {
    int i = blockIdx.x * blockDim.x + threadIdx.x;
    if (i < N_) inv_deg[i] = 1.0f / ((float)deg_cnt[i] + 1e-6f);
}

// ---------------- fused pos MLP + batchnorm (1 block) + pos2 ----------------
__global__ __launch_bounds__(1024) void k_pos_a(const float* __restrict__ pi,
                                                const float* __restrict__ w1,
                                                const float* __restrict__ b1,
                                                const float* __restrict__ g,
                                                const float* __restrict__ be,
                                                float* __restrict__ posn) {
    __shared__ float ph[N_ * 32];
    __shared__ float mu_s[32], rs_s[32];
    int tid = threadIdx.x;
    for (int idx = tid; idx < N_ * 32; idx += 1024) {
        int i = idx >> 5, f = idx & 31;
        float s = b1[f];
        for (int k = 0; k < 9; ++k) s += pi[i * 9 + k] * w1[f * 9 + k];
        ph[idx] = s;
    }
    __syncthreads();
    if (tid < 32) {
        float s = 0.f;
        for (int i = 0; i < N_; ++i) s += ph[i * 32 + tid];
        float m = s / N_;
        float v = 0.f;
        for (int i = 0; i < N_; ++i) { float d = ph[i * 32 + tid] - m; v += d * d; }
        mu_s[tid] = m;
        rs_s[tid] = rsqrtf(v / N_ + 1e-5f);
    }
    __syncthreads();
    for (int idx = tid; idx < N_ * 32; idx += 1024) {
        int f = idx & 31;
        posn[idx] = (ph[idx] - mu_s[f]) * rs_s[f] * g[f] + be[f];
    }
}
__global__ void k_pos2(const float* __restrict__ pn, const float* __restrict__ w,
                       const float* __restrict__ b, float* __restrict__ out) {
    int idx = blockIdx.x * blockDim.x + threadIdx.x;
    if (idx >= N_ * 128) return;
    int i = idx / 128, f = idx % 128;
    float s = b[f];
    for (int k = 0; k < 32; ++k) s += pn[i * 32 + k] * w[f * 32 + k];
    out[idx] = fmaxf(s, 0.f);
}

// ---------------- bf16 concat builders (zero-padded K) ----------------
__global__ void k_build_A1b(const float* __restrict__ x, const int* __restrict__ lab,
                            const float* __restrict__ emb1, const float* __restrict__ pe,
                            ushort_t* __restrict__ A) {
    int idx = blockIdx.x * blockDim.x + threadIdx.x;
    if (idx >= N_ * K1P_) return;
    int i = idx / K1P_, c = idx % K1P_;
    float v = 0.f;
    if (c < CIN_)             v = x[(size_t)i * CIN_ + c];
    else if (c < CIN_ + EMB_) v = emb1[lab[i] * EMB_ + (c - CIN_)];
    else if (c < K1_)         v = pe[i * 128 + (c - CIN_ - EMB_)];
    A[idx] = f2b(v);
}
__global__ void k_build_A2b(const float* __restrict__ x, const int* __restrict__ lab,
                            const float* __restrict__ emb2, const float* __restrict__ ns,
                            ushort_t* __restrict__ A) {
    int idx = blockIdx.x * blockDim.x + threadIdx.x;
    if (idx >= N_ * K2P_) return;
    int i = idx / K2P_, c = idx % K2P_;
    float v = 0.f;
    if (c < CIN_)             v = x[(size_t)i * CIN_ + c];
    else if (c < CIN_ + D_)   v = ns[i * D_ + (c - CIN_)];
    else if (c < K2_)         v = emb2[lab[i] * EMB_ + (c - CIN_ - D_)];
    A[idx] = f2b(v);
}
__global__ void k_build_ekb(const int* __restrict__ rp, const float* __restrict__ ns,
                            ushort_t* __restrict__ ek) {
    int idx = blockIdx.x * blockDim.x + threadIdx.x;
    if (idx >= E_ * 2 * D_) return;
    int e = idx / (2 * D_), c = idx % (2 * D_);
    float v = (c < D_) ? ns[rp[2 * e] * D_ + c] : ns[rp[2 * e + 1] * D_ + (c - D_)];
    ek[idx] = f2b(v);
}

// ---------------- batched f32 -> bf16 convert: row-loop, float4, no division ----------------
struct ConvDesc { const float* src; ushort_t* dst; int K, Kp, rows, rowsp; };
struct ConvArgs { ConvDesc d[16]; };
__global__ void k_conv_batch(ConvArgs a) {
    ConvDesc c = a.d[blockIdx.y];
    for (int row = blockIdx.x; row < c.rowsp; row += gridDim.x) {
        const float* src = c.src + (size_t)row * c.K;
        ushort_t* dst = c.dst + (size_t)row * c.Kp;
        bool inrow = row < c.rows;
        for (int k = threadIdx.x * 4; k < c.Kp; k += blockDim.x * 4) {
            uint2 ov = {0u, 0u};
            if (inrow && k < c.K) {                 // K,Kp both %4==0: no straddle
                float4 v = *(const float4*)(src + k);
                ov.x = (uint_t)f2b(v.x) | ((uint_t)f2b(v.y) << 16);
                ov.y = (uint_t)f2b(v.z) | ((uint_t)f2b(v.w) << 16);
            }
            *(uint2*)(dst + k) = ov;
        }
    }
}
__global__ void k_f2b_n(const float* __restrict__ s, ushort_t* __restrict__ d, int n) {
    int i = blockIdx.x * blockDim.x + threadIdx.x;
    if (i < n) d[i] = f2b(s[i]);
}

// ---------------- scatter / pointwise ----------------
__global__ void k_scatter_edge(const float* __restrict__ er, const int* __restrict__ rep,
                               float* __restrict__ es) {
    int e = blockIdx.x;
    int d = blockIdx.y * 256 + threadIdx.x;
    atomicAdd(&es[(size_t)rep[e] * D_ + d], er[(size_t)e * D_ + d]);
}
__global__ void k_broadcast_es(const int* __restrict__ rep, float* __restrict__ es,
                               ushort_t* __restrict__ esb) {
    int idx = blockIdx.x * blockDim.x + threadIdx.x;
    if (idx >= E_ * D_) return;
    int e = idx / D_, d = idx % D_;
    float v = es[(size_t)rep[e] * D_ + d];
    es[idx] = v;
    esb[idx] = f2b(v);
}
__global__ void k_scatter_e2n(const int* __restrict__ rp, const int* __restrict__ rep,
                              const float* __restrict__ es, float* __restrict__ e2n) {
    int e = blockIdx.x;
    if (rep[e] != e) return;
    int d = blockIdx.y * 256 + threadIdx.x;
    atomicAdd(&e2n[rp[2 * e + 1] * D_ + d], es[(size_t)e * D_ + d]);
}
__global__ void k_scatter_n2n(const int* __restrict__ rp, const int* __restrict__ rep,
                              const float* __restrict__ ns, float* __restrict__ n2n) {
    int e = blockIdx.x;
    if (rep[e] != e) return;
    int d = blockIdx.y * 256 + threadIdx.x;
    atomicAdd(&n2n[rp[2 * e] * D_ + d], ns[rp[2 * e + 1] * D_ + d]);
}
__global__ void k_scale_rows_b(const float* __restrict__ a, const float* __restrict__ inv_deg,
                               ushort_t* __restrict__ ob) {
    int idx = blockIdx.x * blockDim.x + threadIdx.x;
    if (idx >= N_ * D_) return;
    ob[idx] = f2b(a[idx] * inv_deg[idx / D_]);
}
// xinb = f2b(0.5*relu(n2nm_raw + b2[col]) + 0.5*e2nm)
__global__ void k_combine_b(const float* __restrict__ araw, const float* __restrict__ b2,
                            const float* __restrict__ e2nm, ushort_t* __restrict__ o) {
    int idx = blockIdx.x * blockDim.x + threadIdx.x;
    if (idx >= N_ * D_) return;
    float a = fmaxf(araw[idx] + b2[idx & (D_ - 1)], 0.f);
    o[idx] = f2b(0.5f * a + 0.5f * e2nm[idx]);
}
// generic epilogue: v = raw + bias[col]; optional relu; store f32 and/or bf16
__global__ void k_epi(const float* __restrict__ raw, const float* __restrict__ bias,
                      float* __restrict__ fo, ushort_t* __restrict__ bo,
                      int total, int colmask, int relu) {
    int idx = blockIdx.x * blockDim.x + threadIdx.x;
    if (idx >= total) return;
    float v = raw[idx] + bias[idx & colmask];
    if (relu) v = fmaxf(v, 0.f);
    if (fo) fo[idx] = v;
    if (bo) bo[idx] = f2b(v);
}
// rel epilogue: out[row*51+col] = raw[row*64+col] + relb[col], col<51
__global__ void k_epi_rel(const float* __restrict__ raw, const float* __restrict__ relb,
                          float* __restrict__ out) {
    int idx = blockIdx.x * blockDim.x + threadIdx.x;
    if (idx >= E_ * NREL_) return;
    int row = idx / NREL_, col = idx % NREL_;
    out[idx] = raw[row * 64 + col] + relb[col];
}
__global__ void k_gru(const float* __restrict__ gi, const float* __restrict__ gh,
                      const float* __restrict__ bih, const float* __restrict__ bhh,
                      float* __restrict__ h, ushort_t* __restrict__ hb, int M) {
    int idx = blockIdx.x * blockDim.x + threadIdx.x;
    if (idx >= M * D_) return;
    int m = idx / D_, d = idx % D_;
    size_t b3 = (size_t)m * 3 * D_;
    float ir = gi[b3 + d], iz = gi[b3 + D_ + d], ig = gi[b3 + 2 * D_ + d];
    float hr = gh[b3 + d], hz = gh[b3 + D_ + d], hg = gh[b3 + 2 * D_ + d];
    if (bih) { ir += bih[d]; iz += bih[D_ + d]; ig += bih[2 * D_ + d]; }
    if (bhh) { hr += bhh[d]; hz += bhh[D_ + d]; hg += bhh[2 * D_ + d]; }
    float r = 1.f / (1.f + expf(-(ir + hr)));
    float z = 1.f / (1.f + expf(-(iz + hz)));
    float g = tanhf(ig + r * hg);
    size_t hi = (size_t)m * D_ + d;
    float nv = (1.f - z) * g + z * h[hi];
    h[hi] = nv;
    if (hb) hb[hi] = f2b(nv);
}
__global__ void k_obj_dists(const int* __restrict__ lab, float* __restrict__ out) {
    int idx = blockIdx.x * blockDim.x + threadIdx.x;
    if (idx >= N_ * NOBJ_) return;
    out[idx] = (idx % NOBJ_ == lab[idx / NOBJ_]) ? 1000.f : -1000.f;
}

// ---------------- bf16 MFMA GEMM: C[M,N] = A[M,K] @ B[N,K]^T ----------------
typedef __attribute__((ext_vector_type(8))) short sh8;
typedef __attribute__((ext_vector_type(4))) float f32x4;

#define GLOAD_LDS16(gp, lp)                                                        \
    __builtin_amdgcn_global_load_lds((__attribute__((address_space(1))) void*)(gp),\
                                     (__attribute__((address_space(3))) void*)(lp),\
                                     16, 0, 0)

template <int FM, int FN>
__device__ __forceinline__ void gemm_kloop(ushort_t* As, ushort_t* Bs,
                                           const ushort_t* __restrict__ A,
                                           const ushort_t* __restrict__ B,
                                           f32x4 (&acc)[FM][FN],
                                           int K, int ks0, int ks1, int bm, int bn) {
    constexpr int BM = FM * 32, BN = FN * 32;
    constexpr int ATILES = (BM + 63) / 64, BTILES = (BN + 63) / 64;
    const int tid = threadIdx.x;
    const int lane = tid & 63, wid = tid >> 6;
    const int wr = wid >> 1, wc = wid & 1;
    const int ar = tid >> 2, ac = (tid & 3) * 8;
    const int l15 = lane & 15, lg = lane >> 4;
    for (int ks = ks0; ks < ks1; ++ks) {
        int k0 = ks * 32;
#pragma unroll
        for (int i = 0; i < ATILES; ++i) {
            int r = i * 64 + ar;
            if ((BM & 63) == 0 || r < BM)
                GLOAD_LDS16(A + (size_t)(bm + r) * K + k0 + ac, &As[r * 32 + ac]);
        }
#pragma unroll
        for (int i = 0; i < BTILES; ++i) {
            int r = i * 64 + ar;
            if ((BN & 63) == 0 || r < BN)
                GLOAD_LDS16(B + (size_t)(bn + r) * K + k0 + ac, &Bs[r * 32 + ac]);
        }
        __syncthreads();
        sh8 af[FM], bf[FN];
#pragma unroll
        for (int m = 0; m < FM; ++m)
            af[m] = *(const sh8*)&As[(wr * FM * 16 + m * 16 + l15) * 32 + lg * 8];
#pragma unroll
        for (int n = 0; n < FN; ++n)
            bf[n] = *(const sh8*)&Bs[(wc * FN * 16 + n * 16 + l15) * 32 + lg * 8];
#pragma unroll
        for (int m = 0; m < FM; ++m)
#pragma unroll
            for (int n = 0; n < FN; ++n)
                acc[m][n] = __builtin_amdgcn_mfma_f32_16x16x32_bf16(af[m], bf[n], acc[m][n], 0, 0, 0);
        __syncthreads();
    }
}

template <int FM, int FN>
__global__ __launch_bounds__(256) void gemm_mfma(const ushort_t* __restrict__ A,
                                                 const ushort_t* __restrict__ B,
                                                 const float* __restrict__ bias,
                                                 float* __restrict__ C,
                                                 ushort_t* __restrict__ Cb,
                                                 int M, int N, int K, int relu) {
    __shared__ ushort_t As[FM * 32 * 32];
    __shared__ ushort_t Bs[FN * 32 * 32];
    const int bm = blockIdx.y * FM * 32, bn = blockIdx.x * FN * 32;
    f32x4 acc[FM][FN];
#pragma unroll
    for (int m = 0; m < FM; ++m)
#pragma unroll
        for (int n = 0; n < FN; ++n) acc[m][n] = (f32x4){0.f, 0.f, 0.f, 0.f};
    gemm_kloop<FM, FN>(As, Bs, A, B, acc, K, 0, K / 32, bm, bn);
    const int lane = threadIdx.x & 63, wid = threadIdx.x >> 6;
    const int l15 = lane & 15, lg = lane >> 4;
    const int r0 = bm + (wid >> 1) * FM * 16, c0 = bn + (wid & 1) * FN * 16;
#pragma unroll
    for (int m = 0; m < FM; ++m)
#pragma unroll
        for (int n = 0; n < FN; ++n)
#pragma unroll
            for (int j = 0; j < 4; ++j) {
                int row = r0 + m * 16 + lg * 4 + j;
                int col = c0 + n * 16 + l15;
                if (row < M && col < N) {
                    float v = acc[m][n][j] + (bias ? bias[col] : 0.f);
                    if (relu) v = fmaxf(v, 0.f);
                    if (C)  C[(size_t)row * N + col] = v;
                    if (Cb) Cb[(size_t)row * N + col] = f2b(v);
                }
            }
}

// split-K: grid.z splits accumulate via f32 atomicAdd into pre-zeroed C (no bias/relu)
template <int FM, int FN>
__global__ __launch_bounds__(256) void gemm_splitk(const ushort_t* __restrict__ A,
                                                   const ushort_t* __restrict__ B,
                                                   float* __restrict__ C,
                                                   int M, int N, int K, int S) {
    __shared__ ushort_t As[FM * 32 * 32];
    __shared__ ushort_t Bs[FN * 32 * 32];
    const int nsteps = K / 32;
    const int ss = (nsteps + S - 1) / S;
    const int ks0 = blockIdx.z * ss;
    const int ks1 = min(nsteps, ks0 + ss);
    if (ks0 >= ks1) return;
    const int bm = blockIdx.y * FM * 32, bn = blockIdx.x * FN * 32;
    f32x4 acc[FM][FN];
#pragma unroll
    for (int m = 0; m < FM; ++m)
#pragma unroll
        for (int n = 0; n < FN; ++n) acc[m][n] = (f32x4){0.f, 0.f, 0.f, 0.f};
    gemm_kloop<FM, FN>(As, Bs, A, B, acc, K, ks0, ks1, bm, bn);
    const int lane = threadIdx.x & 63, wid = threadIdx.x >> 6;
    const int l15 = lane & 15, lg = lane >> 4;
    const int r0 = bm + (wid >> 1) * FM * 16, c0 = bn + (wid & 1) * FN * 16;
#pragma unroll
    for (int m = 0; m < FM; ++m)
#pragma unroll
        for (int n = 0; n < FN; ++n)
#pragma unroll
            for (int j = 0; j < 4; ++j) {
                int row = r0 + m * 16 + lg * 4 + j;
                int col = c0 + n * 16 + l15;
                if (row < M && col < N)
                    atomicAdd(&C[(size_t)row * N + col], acc[m][n][j]);
            }
}

static inline dim3 mgrid(int M, int N, int FM, int FN) {
    return dim3((N + FN * 32 - 1) / (FN * 32), (M + FM * 32 - 1) / (FM * 32));
}
static inline dim3 sgrid(int M, int N, int FM, int FN, int S) {
    dim3 g = mgrid(M, N, FM, FN);
    return dim3(g.x, g.y, S);
}

extern "C" void kernel_launch(void* const* d_in, const int* in_sizes, int n_in,
                              void* d_out, int out_size, void* d_ws, size_t ws_size,
                              hipStream_t stream) {
    const float* x      = (const float*)d_in[0];
    const float* posi   = (const float*)d_in[1];
    const float* unionf = (const float*)d_in[2];
    const int*   lab    = (const int*)d_in[3];
    const int*   rp     = (const int*)d_in[4];
    const float* emb1   = (const float*)d_in[5];
    const float* emb2   = (const float*)d_in[6];
    const float* nw     = (const float*)d_in[7];
    const float* nb     = (const float*)d_in[8];
    const float* nw2    = (const float*)d_in[9];
    const float* nb2    = (const float*)d_in[10];
    const float* ew     = (const float*)d_in[11];
    const float* eb     = (const float*)d_in[12];
    const float* pw1    = (const float*)d_in[13];
    const float* pb1    = (const float*)d_in[14];
    const float* pg     = (const float*)d_in[15];
    const float* pbe    = (const float*)d_in[16];
    const float* pw2    = (const float*)d_in[17];
    const float* pb2    = (const float*)d_in[18];
    const float* ngwih  = (const float*)d_in[19];
    const float* ngwhh  = (const float*)d_in[20];
    const float* ngbih  = (const float*)d_in[21];
    const float* ngbhh  = (const float*)d_in[22];
    const float* egwih  = (const float*)d_in[23];
    const float* egwhh  = (const float*)d_in[24];
    const float* n2nw1  = (const float*)d_in[25];
    const float* n2nb1  = (const float*)d_in[26];
    const float* n2nw2  = (const float*)d_in[27];
    const float* n2nb2  = (const float*)d_in[28];
    const float* e2nw1  = (const float*)d_in[29];
    const float* e2nb1  = (const float*)d_in[30];
    const float* e2nw2  = (const float*)d_in[31];
    const float* e2nb2  = (const float*)d_in[32];
    const float* n2ew1  = (const float*)d_in[33];
    const float* n2eb1  = (const float*)d_in[34];
    const float* n2ew2  = (const float*)d_in[35];
    const float* n2eb2  = (const float*)d_in[36];
    const float* relw   = (const float*)d_in[37];
    const float* relb   = (const float*)d_in[38];

    size_t off = 0;
    auto alloc = [&](size_t bytes) {
        off = (off + 255) & ~(size_t)255;
        char* p = (char*)d_ws + off;
        off += bytes;
        return (void*)p;
    };
    int*      mapMin  = (int*)alloc((size_t)N_ * N_ * 4);
    int*      rep     = (int*)alloc(E_ * 4);
    int*      deg_cnt = (int*)alloc(N_ * 4);
    float*    inv_deg = (float*)alloc(N_ * 4);
    float*    posn    = (float*)alloc(N_ * 32 * 4);
    float*    pe      = (float*)alloc(N_ * 128 * 4);
    float*    ns      = (float*)alloc((size_t)N_ * D_ * 4);
    ushort_t* nsb     = (ushort_t*)alloc((size_t)N_ * D_ * 2);
    float*    nsraw   = (float*)alloc((size_t)N_ * D_ * 4);
    // scratch region: [n2n | tmpraw | n2nmraw | gin | ghn] -- one memset per use
    char*     scrR    = (char*)alloc((size_t)(2 * N_ * D_ + N_ * D_ + 2 * N_ * 3 * D_) * 4);
    float*    n2n     = (float*)scrR;
    float*    tmpraw  = (float*)(scrR + (size_t)N_ * D_ * 4);
    float*    n2nmraw = (float*)(scrR + (size_t)2 * N_ * D_ * 4);
    float*    gin     = (float*)(scrR + (size_t)3 * N_ * D_ * 4);
    float*    ghn     = (float*)(scrR + (size_t)(3 * N_ * D_ + N_ * 3 * D_) * 4);
    const size_t scrBytes = (size_t)(3 * N_ * D_ + 2 * N_ * 3 * D_) * 4;
    float*    e2nm    = (float*)alloc((size_t)N_ * D_ * 4);
    float*    relraw  = (float*)alloc((size_t)E_ * 64 * 4);
    // union: A1b / A2b / ekb -- sequential lifetimes
    char*     unionU  = (char*)alloc((size_t)E_ * 2 * D_ * 2);
    ushort_t* A1b = (ushort_t*)unionU;
    ushort_t* A2b = (ushort_t*)unionU;
    ushort_t* ekb = (ushort_t*)unionU;
    // union: ufb bf16 (early) / gie f32 (late)
    char*     ufbU = (char*)alloc((size_t)E_ * CIN_ * 2);
    ushort_t* ufb = (ushort_t*)ufbU;
    float*    gie = (float*)ufbU;
    // union: erep f32 (early) / erepb+msgb bf16 (late)
    char*     erepU = (char*)alloc((size_t)E_ * D_ * 4);
    float*    erep  = (float*)erepU;
    ushort_t* erepb = (ushort_t*)erepU;
    ushort_t* msgb  = (ushort_t*)(erepU + (size_t)E_ * D_ * 2);
    float*    es    = (float*)alloc((size_t)E_ * D_ * 4);
    ushort_t* esb   = (ushort_t*)alloc((size_t)E_ * D_ * 2);
    float*    e2n   = (float*)alloc((size_t)N_ * D_ * 4);
    ushort_t* e2nb  = (ushort_t*)alloc((size_t)N_ * D_ * 2);
    ushort_t* tmpb  = (ushort_t*)alloc((size_t)N_ * D_ * 2);
    ushort_t* n2nb  = (ushort_t*)alloc((size_t)N_ * D_ * 2);
    ushort_t* xinb  = (ushort_t*)alloc((size_t)N_ * D_ * 2);
    float*    ghe   = (float*)alloc((size_t)E_ * 3 * D_ * 4);
    // bf16 weights
    ushort_t* nwb     = (ushort_t*)alloc((size_t)D_ * K1P_ * 2);
    ushort_t* nw2b    = (ushort_t*)alloc((size_t)D_ * K2P_ * 2);
    ushort_t* ewb     = (ushort_t*)alloc((size_t)D_ * CIN_ * 2);
    ushort_t* ngwihb  = (ushort_t*)alloc((size_t)3 * D_ * D_ * 2);
    ushort_t* ngwhhb  = (ushort_t*)alloc((size_t)3 * D_ * D_ * 2);
    ushort_t* egwihb  = (ushort_t*)alloc((size_t)3 * D_ * D_ * 2);
    ushort_t* egwhhb  = (ushort_t*)alloc((size_t)3 * D_ * D_ * 2);
    ushort_t* n2nw1b  = (ushort_t*)alloc((size_t)D_ * D_ * 2);
    ushort_t* n2nw2b  = (ushort_t*)alloc((size_t)D_ * D_ * 2);
    ushort_t* e2nw1b  = (ushort_t*)alloc((size_t)D_ * D_ * 2);
    ushort_t* e2nw2b  = (ushort_t*)alloc((size_t)D_ * D_ * 2);
    ushort_t* n2ew1b  = (ushort_t*)alloc((size_t)D_ * 2 * D_ * 2);
    ushort_t* n2ew2b  = (ushort_t*)alloc((size_t)D_ * D_ * 2);
    ushort_t* relwb   = (ushort_t*)alloc((size_t)64 * D_ * 2);
    if (off > ws_size) return;

    float* out_obj = (float*)d_out;
    float* out_rel = (float*)d_out + N_ * NOBJ_;

    // ---- weight + union_features bf16 conversion ----
    ConvArgs ca;
    int ci = 0;
    auto addc = [&](const float* s, ushort_t* dptr, int K, int Kp, int rows, int rowsp) {
        ca.d[ci++] = ConvDesc{s, dptr, K, Kp, rows, rowsp};
    };
    addc(nw,    nwb,    K1_,      K1P_,     D_,       D_);
    addc(nw2,   nw2b,   K2_,      K2P_,     D_,       D_);
    addc(ew,    ewb,    CIN_,     CIN_,     D_,       D_);
    addc(ngwih, ngwihb, D_,       D_,       3 * D_,   3 * D_);
    addc(ngwhh, ngwhhb, D_,       D_,       3 * D_,   3 * D_);
    addc(egwih, egwihb, D_,       D_,       3 * D_,   3 * D_);
    addc(egwhh, egwhhb, D_,       D_,       3 * D_,   3 * D_);
    addc(n2nw1, n2nw1b, D_,       D_,       D_,       D_);
    addc(n2nw2, n2nw2b, D_,       D_,       D_,       D_);
    addc(e2nw1, e2nw1b, D_,       D_,       D_,       D_);
    addc(e2nw2, e2nw2b, D_,       D_,       D_,       D_);
    addc(n2ew1, n2ew1b, 2 * D_,   2 * D_,   D_,       D_);
    addc(n2ew2, n2ew2b, D_,       D_,       D_,       D_);
    addc(relw,  relwb,  D_,       D_,       NREL_,    64);
    addc(unionf, ufb,   CIN_,     CIN_,     E_,       E_);
    for (; ci < 16;) ca.d[ci++] = ConvDesc{nullptr, nullptr, 4, 4, 0, 0};
    k_conv_batch<<<dim3(512, 15), 256, 0, stream>>>(ca);

    // ---- pair dedup + degrees ----
    (void)hipMemsetAsync(mapMin, 0x7F, (size_t)N_ * N_ * 4, stream);
    (void)hipMemsetAsync(deg_cnt, 0, N_ * 4, stream);
    k_pair_min<<<(E_ + 255) / 256, 256, 0, stream>>>(rp, mapMin);
    k_pair_rep<<<(E_ + 255) / 256, 256, 0, stream>>>(rp, mapMin, rep, deg_cnt);
    k_inv_deg<<<(N_ + 255) / 256, 256, 0, stream>>>(deg_cnt, inv_deg);

    // ---- pos embed ----
    k_pos_a<<<1, 1024, 0, stream>>>(posi, pw1, pb1, pg, pbe, posn);
    k_pos2<<<(N_ * 128 + 255) / 256, 256, 0, stream>>>(posn, pw2, pb2, pe);

    // ---- node_states = [x|emb1|pos] @ nw^T + nb (split-K S=8) ----
    k_build_A1b<<<((size_t)N_ * K1P_ + 255) / 256, 256, 0, stream>>>(x, lab, emb1, pe, A1b);
    (void)hipMemsetAsync(nsraw, 0, (size_t)N_ * D_ * 4, stream);
    gemm_splitk<1, 1><<<sgrid(N_, D_, 1, 1, 8), 256, 0, stream>>>(A1b, nwb, nsraw, N_, D_, K1P_, 8);
    k_epi<<<(N_ * D_ + 255) / 256, 256, 0, stream>>>(nsraw, nb, ns, nsb, N_ * D_, D_ - 1, 0);

    // ---- edge_rep (split-K S=2) + sparse edge_states ----
    (void)hipMemsetAsync(erep, 0, (size_t)E_ * D_ * 4, stream);
    gemm_splitk<2, 2><<<sgrid(E_, D_, 2, 2, 2), 256, 0, stream>>>(ufb, ewb, erep, E_, D_, CIN_, 2);
    k_epi<<<((size_t)E_ * D_ + 255) / 256, 256, 0, stream>>>(erep, eb, erep, nullptr, E_ * D_, D_ - 1, 0);
    (void)hipMemsetAsync(es, 0, (size_t)E_ * D_ * 4, stream);
    k_scatter_edge<<<dim3(E_, 2), 256, 0, stream>>>(erep, rep, es);
    k_broadcast_es<<<(E_ * D_ + 255) / 256, 256, 0, stream>>>(rep, es, esb);

    // ---- e2n (loop-invariant): scatter + split-K MLP ----
    (void)hipMemsetAsync(e2n, 0, (size_t)N_ * D_ * 4, stream);
    k_scatter_e2n<<<dim3(E_, 2), 256, 0, stream>>>(rp, rep, es, e2n);
    k_f2b_n<<<(N_ * D_ + 255) / 256, 256, 0, stream>>>(e2n, e2nb, N_ * D_);
    (void)hipMemsetAsync(scrR, 0, scrBytes, stream);
    gemm_splitk<1, 1><<<sgrid(N_, D_, 1, 1, 8), 256, 0, stream>>>(e2nb, e2nw1b, tmpraw, N_, D_, D_, 8);
    k_epi<<<(N_ * D_ + 255) / 256, 256, 0, stream>>>(tmpraw, e2nb1, nullptr, tmpb, N_ * D_, D_ - 1, 1);
    gemm_splitk<1, 1><<<sgrid(N_, D_, 1, 1, 8), 256, 0, stream>>>(tmpb, e2nw2b, n2nmraw, N_, D_, D_, 8);
    k_epi<<<(N_ * D_ + 255) / 256, 256, 0, stream>>>(n2nmraw, e2nb2, e2nm, nullptr, N_ * D_, D_ - 1, 1);

    // ---- node GRU loop x3 ----
    for (int it = 0; it < 3; ++it) {
        (void)hipMemsetAsync(scrR, 0, scrBytes, stream);
        k_scatter_n2n<<<dim3(E_, 2), 256, 0, stream>>>(rp, rep, ns, n2n);
        k_scale_rows_b<<<(N_ * D_ + 255) / 256, 256, 0, stream>>>(n2n, inv_deg, n2nb);
        gemm_splitk<1, 1><<<sgrid(N_, D_, 1, 1, 8), 256, 0, stream>>>(n2nb, n2nw1b, tmpraw, N_, D_, D_, 8);
        k_epi<<<(N_ * D_ + 255) / 256, 256, 0, stream>>>(tmpraw, n2nb1, nullptr, tmpb, N_ * D_, D_ - 1, 1);
        gemm_splitk<1, 1><<<sgrid(N_, D_, 1, 1, 8), 256, 0, stream>>>(tmpb, n2nw2b, n2nmraw, N_, D_, D_, 8);
        k_combine_b<<<(N_ * D_ + 255) / 256, 256, 0, stream>>>(n2nmraw, n2nb2, e2nm, xinb);
        gemm_splitk<1, 1><<<sgrid(N_, 3 * D_, 1, 1, 4), 256, 0, stream>>>(xinb, ngwihb, gin, N_, 3 * D_, D_, 4);
        gemm_splitk<1, 1><<<sgrid(N_, 3 * D_, 1, 1, 4), 256, 0, stream>>>(nsb, ngwhhb, ghn, N_, 3 * D_, D_, 4);
        k_gru<<<(N_ * D_ + 255) / 256, 256, 0, stream>>>(gin, ghn, ngbih, ngbhh, ns, nsb, N_);
    }

    // ---- obj_dists ----
    k_obj_dists<<<(N_ * NOBJ_ + 255) / 256, 256, 0, stream>>>(lab, out_obj);

    // ---- node_states2 (split-K S=8) ----
    k_build_A2b<<<((size_t)N_ * K2P_ + 255) / 256, 256, 0, stream>>>(x, lab, emb2, ns, A2b);
    (void)hipMemsetAsync(nsraw, 0, (size_t)N_ * D_ * 4, stream);
    gemm_splitk<1, 1><<<sgrid(N_, D_, 1, 1, 8), 256, 0, stream>>>(A2b, nw2b, nsraw, N_, D_, K2P_, 8);
    k_epi<<<(N_ * D_ + 255) / 256, 256, 0, stream>>>(nsraw, nb2, ns, nsb, N_ * D_, D_ - 1, 0);

    // ---- edge loop: msg + gi loop-invariant ----
    k_build_ekb<<<((size_t)E_ * 2 * D_ + 255) / 256, 256, 0, stream>>>(rp, ns, ekb);
    gemm_mfma<2, 2><<<mgrid(E_, D_, 2, 2), 256, 0, stream>>>(ekb, n2ew1b, n2eb1, nullptr, erepb, E_, D_, 2 * D_, 1);
    gemm_mfma<2, 2><<<mgrid(E_, D_, 2, 2), 256, 0, stream>>>(erepb, n2ew2b, n2eb2, nullptr, msgb, E_, D_, D_, 1);
    gemm_mfma<2, 4><<<mgrid(E_, 3 * D_, 2, 4), 256, 0, stream>>>(msgb, egwihb, nullptr, gie, nullptr, E_, 3 * D_, D_, 0);
    for (int it = 0; it < 3; ++it) {
        gemm_mfma<2, 4><<<mgrid(E_, 3 * D_, 2, 4), 256, 0, stream>>>(esb, egwhhb, nullptr, ghe, nullptr, E_, 3 * D_, D_, 0);
        k_gru<<<(E_ * D_ + 255) / 256, 256, 0, stream>>>(gie, ghe, nullptr, nullptr, es, esb, E_);
    }

    // ---- rel_dists: split-K into padded raw, then bias epilogue ----
    (void)hipMemsetAsync(relraw, 0, (size_t)E_ * 64 * 4, stream);
    gemm_splitk<1, 1><<<sgrid(E_, 64, 1, 1, 4), 256, 0, stream>>>(esb, relwb, relraw, E_, 64, D_, 4);
    k_epi_rel<<<(E_ * NREL_ + 255) / 256, 256, 0, stream>>>(relraw, relb, out_rel);
}

// Round 8
// 664.427 us; speedup vs baseline: 7.6984x; 1.0611x over previous
//
#include <hip/hip_runtime.h>

typedef unsigned short ushort_t;
typedef unsigned int uint_t;

#define N_    384
#define E_    3072
#define CIN_  4096
#define EMB_  200
#define D_    512
#define NOBJ_ 151
#define NREL_ 51
#define K1_   (CIN_ + EMB_ + 128)   // 4424
#define K1P_  4448                  // pad to %32
#define K2_   (CIN_ + EMB_ + D_)    // 4808
#define K2P_  4832

__device__ __forceinline__ ushort_t f2b(float f) {
    uint_t u = __float_as_uint(f);
    u += 0x7FFFu + ((u >> 16) & 1u);           // RNE
    return (ushort_t)(u >> 16);
}

// ---------------- pair dedup ----------------
__global__ void k_pair_min(const int* __restrict__ rp, int* __restrict__ mapMin) {
    int e = blockIdx.x * blockDim.x + threadIdx.x;
    if (e >= E_) return;
    atomicMin(&mapMin[rp[2 * e] * N_ + rp[2 * e + 1]], e);
}
__global__ void k_pair_rep(const int* __restrict__ rp, const int* __restrict__ mapMin,
                           int* __restrict__ rep, int* __restrict__ deg_cnt) {
    int e = blockIdx.x * blockDim.x + threadIdx.x;
    if (e >= E_) return;
    int r = mapMin[rp[2 * e] * N_ + rp[2 * e + 1]];
    rep[e] = r;
    if (r == e) atomicAdd(&deg_cnt[rp[2 * e]], 1);
}
__global__ void k_inv_deg(const int* __restrict__ deg_cnt, float* __restrict__ inv_deg) {
    int i = blockIdx.x * blockDim.x + threadIdx.x;
    if (i < N_) inv_deg[i] = 1.0f / ((float)deg_cnt[i] + 1e-6f);
}

// ---------------- fused pos MLP + batchnorm (1 block) + pos2 ----------------
__global__ __launch_bounds__(1024) void k_pos_a(const float* __restrict__ pi,
                                                const float* __restrict__ w1,
                                                const float* __restrict__ b1,
                                                const float* __restrict__ g,
                                                const float* __restrict__ be,
                                                float* __restrict__ posn) {
    __shared__ float ph[N_ * 32];
    __shared__ float mu_s[32], rs_s[32];
    int tid = threadIdx.x;
    for (int idx = tid; idx < N_ * 32; idx += 1024) {
        int i = idx >> 5, f = idx & 31;
        float s = b1[f];
        for (int k = 0; k < 9; ++k) s += pi[i * 9 + k] * w1[f * 9 + k];
        ph[idx] = s;
    }
    __syncthreads();
    if (tid < 32) {
        float s = 0.f;
        for (int i = 0; i < N_; ++i) s += ph[i * 32 + tid];
        float m = s / N_;
        float v = 0.f;
        for (int i = 0; i < N_; ++i) { float d = ph[i * 32 + tid] - m; v += d * d; }
        mu_s[tid] = m;
        rs_s[tid] = rsqrtf(v / N_ + 1e-5f);
    }
    __syncthreads();
    for (int idx = tid; idx < N_ * 32; idx += 1024) {
        int f = idx & 31;
        posn[idx] = (ph[idx] - mu_s[f]) * rs_s[f] * g[f] + be[f];
    }
}
__global__ void k_pos2(const float* __restrict__ pn, const float* __restrict__ w,
                       const float* __restrict__ b, float* __restrict__ out) {
    int idx = blockIdx.x * blockDim.x + threadIdx.x;
    if (idx >= N_ * 128) return;
    int i = idx / 128, f = idx % 128;
    float s = b[f];
    for (int k = 0; k < 32; ++k) s += pn[i * 32 + k] * w[f * 32 + k];
    out[idx] = fmaxf(s, 0.f);
}

// ---------------- bf16 concat builders (zero-padded K) ----------------
__global__ void k_build_A1b(const float* __restrict__ x, const int* __restrict__ lab,
                            const float* __restrict__ emb1, const float* __restrict__ pe,
                            ushort_t* __restrict__ A) {
    int idx = blockIdx.x * blockDim.x + threadIdx.x;
    if (idx >= N_ * K1P_) return;
    int i = idx / K1P_, c = idx % K1P_;
    float v = 0.f;
    if (c < CIN_)             v = x[(size_t)i * CIN_ + c];
    else if (c < CIN_ + EMB_) v = emb1[lab[i] * EMB_ + (c - CIN_)];
    else if (c < K1_)         v = pe[i * 128 + (c - CIN_ - EMB_)];
    A[idx] = f2b(v);
}
__global__ void k_build_A2b(const float* __restrict__ x, const int* __restrict__ lab,
                            const float* __restrict__ emb2, const ushort_t* __restrict__ nsb,
                            ushort_t* __restrict__ A) {
    int idx = blockIdx.x * blockDim.x + threadIdx.x;
    if (idx >= N_ * K2P_) return;
    int i = idx / K2P_, c = idx % K2P_;
    ushort_t o = 0;
    if (c < CIN_)             o = f2b(x[(size_t)i * CIN_ + c]);
    else if (c < CIN_ + D_)   o = nsb[i * D_ + (c - CIN_)];
    else if (c < K2_)         o = f2b(emb2[lab[i] * EMB_ + (c - CIN_ - D_)]);
    A[idx] = o;
}
__global__ void k_build_ekb(const int* __restrict__ rp, const ushort_t* __restrict__ nsb,
                            ushort_t* __restrict__ ek) {
    int idx = blockIdx.x * blockDim.x + threadIdx.x;
    if (idx >= E_ * 2 * D_) return;
    int e = idx / (2 * D_), c = idx % (2 * D_);
    ek[idx] = (c < D_) ? nsb[rp[2 * e] * D_ + c] : nsb[rp[2 * e + 1] * D_ + (c - D_)];
}

// ---------------- batched f32 -> bf16 convert: row-loop, float4 ----------------
struct ConvDesc { const float* src; ushort_t* dst; int K, Kp, rows, rowsp; };
struct ConvArgs { ConvDesc d[16]; };
__global__ void k_conv_batch(ConvArgs a) {
    ConvDesc c = a.d[blockIdx.y];
    for (int row = blockIdx.x; row < c.rowsp; row += gridDim.x) {
        const float* src = c.src + (size_t)row * c.K;
        ushort_t* dst = c.dst + (size_t)row * c.Kp;
        bool inrow = row < c.rows;
        for (int k = threadIdx.x * 4; k < c.Kp; k += blockDim.x * 4) {
            uint2 ov = {0u, 0u};
            if (inrow && k < c.K) {
                float4 v = *(const float4*)(src + k);
                ov.x = (uint_t)f2b(v.x) | ((uint_t)f2b(v.y) << 16);
                ov.y = (uint_t)f2b(v.z) | ((uint_t)f2b(v.w) << 16);
            }
            *(uint2*)(dst + k) = ov;
        }
    }
}
__global__ void k_f2b_n(const float* __restrict__ s, ushort_t* __restrict__ d, int n) {
    int i = blockIdx.x * blockDim.x + threadIdx.x;
    if (i < n) d[i] = f2b(s[i]);
}

// ---------------- scatter / pointwise ----------------
__global__ void k_scatter_edge(const float* __restrict__ er, const int* __restrict__ rep,
                               float* __restrict__ es) {
    int e = blockIdx.x;
    int d = blockIdx.y * 256 + threadIdx.x;
    atomicAdd(&es[(size_t)rep[e] * D_ + d], er[(size_t)e * D_ + d]);
}
__global__ void k_broadcast_es(const int* __restrict__ rep, float* __restrict__ es,
                               ushort_t* __restrict__ esb) {
    int idx = blockIdx.x * blockDim.x + threadIdx.x;
    if (idx >= E_ * D_) return;
    int e = idx / D_, d = idx % D_;
    float v = es[(size_t)rep[e] * D_ + d];
    es[idx] = v;
    esb[idx] = f2b(v);
}
__global__ void k_scatter_e2n(const int* __restrict__ rp, const int* __restrict__ rep,
                              const float* __restrict__ es, float* __restrict__ e2n) {
    int e = blockIdx.x;
    if (rep[e] != e) return;
    int d = blockIdx.y * 256 + threadIdx.x;
    atomicAdd(&e2n[rp[2 * e + 1] * D_ + d], es[(size_t)e * D_ + d]);
}
__global__ void k_scatter_n2n(const int* __restrict__ rp, const int* __restrict__ rep,
                              const float* __restrict__ ns, float* __restrict__ n2n) {
    int e = blockIdx.x;
    if (rep[e] != e) return;
    int d = blockIdx.y * 256 + threadIdx.x;
    atomicAdd(&n2n[rp[2 * e] * D_ + d], ns[rp[2 * e + 1] * D_ + d]);
}
__global__ void k_scale_rows_b(const float* __restrict__ a, const float* __restrict__ inv_deg,
                               ushort_t* __restrict__ ob) {
    int idx = blockIdx.x * blockDim.x + threadIdx.x;
    if (idx >= N_ * D_) return;
    ob[idx] = f2b(a[idx] * inv_deg[idx / D_]);
}
// xinb = f2b(0.5*relu(n2nm_raw + b2[col]) + 0.5*e2nm)
__global__ void k_combine_b(const float* __restrict__ araw, const float* __restrict__ b2,
                            const float* __restrict__ e2nm, ushort_t* __restrict__ o) {
    int idx = blockIdx.x * blockDim.x + threadIdx.x;
    if (idx >= N_ * D_) return;
    float a = fmaxf(araw[idx] + b2[idx & (D_ - 1)], 0.f);
    o[idx] = f2b(0.5f * a + 0.5f * e2nm[idx]);
}
__global__ void k_epi(const float* __restrict__ raw, const float* __restrict__ bias,
                      float* __restrict__ fo, ushort_t* __restrict__ bo,
                      int total, int colmask, int relu) {
    int idx = blockIdx.x * blockDim.x + threadIdx.x;
    if (idx >= total) return;
    float v = raw[idx] + bias[idx & colmask];
    if (relu) v = fmaxf(v, 0.f);
    if (fo) fo[idx] = v;
    if (bo) bo[idx] = f2b(v);
}
__global__ void k_epi_rel(const float* __restrict__ raw, const float* __restrict__ relb,
                          float* __restrict__ out) {
    int idx = blockIdx.x * blockDim.x + threadIdx.x;
    if (idx >= E_ * NREL_) return;
    int row = idx / NREL_, col = idx % NREL_;
    out[idx] = raw[row * 64 + col] + relb[col];
}
__global__ void k_gru(const float* __restrict__ gi, const float* __restrict__ gh,
                      const float* __restrict__ bih, const float* __restrict__ bhh,
                      float* __restrict__ h, ushort_t* __restrict__ hb, int M) {
    int idx = blockIdx.x * blockDim.x + threadIdx.x;
    if (idx >= M * D_) return;
    int m = idx / D_, d = idx % D_;
    size_t b3 = (size_t)m * 3 * D_;
    float ir = gi[b3 + d], iz = gi[b3 + D_ + d], ig = gi[b3 + 2 * D_ + d];
    float hr = gh[b3 + d], hz = gh[b3 + D_ + d], hg = gh[b3 + 2 * D_ + d];
    if (bih) { ir += bih[d]; iz += bih[D_ + d]; ig += bih[2 * D_ + d]; }
    if (bhh) { hr += bhh[d]; hz += bhh[D_ + d]; hg += bhh[2 * D_ + d]; }
    float r = 1.f / (1.f + expf(-(ir + hr)));
    float z = 1.f / (1.f + expf(-(iz + hz)));
    float g = tanhf(ig + r * hg);
    size_t hi = (size_t)m * D_ + d;
    float nv = (1.f - z) * g + z * h[hi];
    h[hi] = nv;
    if (hb) hb[hi] = f2b(nv);
}
__global__ void k_obj_dists(const int* __restrict__ lab, float* __restrict__ out) {
    int idx = blockIdx.x * blockDim.x + threadIdx.x;
    if (idx >= N_ * NOBJ_) return;
    out[idx] = (idx % NOBJ_ == lab[idx / NOBJ_]) ? 1000.f : -1000.f;
}

// ---------------- bf16 MFMA GEMM: C[M,N] = A[M,K] @ B[N,K]^T ----------------
typedef __attribute__((ext_vector_type(8))) short sh8;
typedef __attribute__((ext_vector_type(4))) float f32x4;

#define GLOAD_LDS16(gp, lp)                                                        \
    __builtin_amdgcn_global_load_lds((__attribute__((address_space(1))) void*)(gp),\
                                     (__attribute__((address_space(3))) void*)(lp),\
                                     16, 0, 0)

// XCD-aware remap: groups all (x,z) blocks of one y-panel onto one XCD.
// Requires gridDim.y % 8 == 0. [heuristic: wgid%8 = XCD on MI355X]
template <bool SWZ>
__device__ __forceinline__ void get_bxyz(int& bx, int& by, int& bz) {
    if (!SWZ) { bx = blockIdx.x; by = blockIdx.y; bz = blockIdx.z; return; }
    int nx = gridDim.x, nz = gridDim.z;
    int bid = blockIdx.x + nx * (blockIdx.y + gridDim.y * blockIdx.z);
    int r8 = bid & 7, i = bid >> 3;
    int per = nx * nz;
    int ygrp = i / per;
    int rem = i - ygrp * per;
    bx = rem % nx;
    bz = rem / nx;
    by = r8 + 8 * ygrp;
}

template <int FM, int FN>
__device__ __forceinline__ void gemm_kloop(ushort_t* As, ushort_t* Bs,
                                           const ushort_t* __restrict__ A,
                                           const ushort_t* __restrict__ B,
                                           f32x4 (&acc)[FM][FN],
                                           int K, int ks0, int ks1, int bm, int bn) {
    constexpr int BM = FM * 32, BN = FN * 32;
    constexpr int ATILES = (BM + 63) / 64, BTILES = (BN + 63) / 64;
    const int tid = threadIdx.x;
    const int lane = tid & 63, wid = tid >> 6;
    const int wr = wid >> 1, wc = wid & 1;
    const int ar = tid >> 2, ac = (tid & 3) * 8;
    const int l15 = lane & 15, lg = lane >> 4;
    for (int ks = ks0; ks < ks1; ++ks) {
        int k0 = ks * 32;
#pragma unroll
        for (int i = 0; i < ATILES; ++i) {
            int r = i * 64 + ar;
            if ((BM & 63) == 0 || r < BM)
                GLOAD_LDS16(A + (size_t)(bm + r) * K + k0 + ac, &As[r * 32 + ac]);
        }
#pragma unroll
        for (int i = 0; i < BTILES; ++i) {
            int r = i * 64 + ar;
            if ((BN & 63) == 0 || r < BN)
                GLOAD_LDS16(B + (size_t)(bn + r) * K + k0 + ac, &Bs[r * 32 + ac]);
        }
        __syncthreads();
        sh8 af[FM], bf[FN];
#pragma unroll
        for (int m = 0; m < FM; ++m)
            af[m] = *(const sh8*)&As[(wr * FM * 16 + m * 16 + l15) * 32 + lg * 8];
#pragma unroll
        for (int n = 0; n < FN; ++n)
            bf[n] = *(const sh8*)&Bs[(wc * FN * 16 + n * 16 + l15) * 32 + lg * 8];
#pragma unroll
        for (int m = 0; m < FM; ++m)
#pragma unroll
            for (int n = 0; n < FN; ++n)
                acc[m][n] = __builtin_amdgcn_mfma_f32_16x16x32_bf16(af[m], bf[n], acc[m][n], 0, 0, 0);
        __syncthreads();
    }
}

template <int FM, int FN, bool SWZ = false>
__global__ __launch_bounds__(256) void gemm_mfma(const ushort_t* __restrict__ A,
                                                 const ushort_t* __restrict__ B,
                                                 const float* __restrict__ bias,
                                                 float* __restrict__ C,
                                                 ushort_t* __restrict__ Cb,
                                                 int M, int N, int K, int relu) {
    __shared__ ushort_t As[FM * 32 * 32];
    __shared__ ushort_t Bs[FN * 32 * 32];
    int bx, by, bz;
    get_bxyz<SWZ>(bx, by, bz);
    const int bm = by * FM * 32, bn = bx * FN * 32;
    f32x4 acc[FM][FN];
#pragma unroll
    for (int m = 0; m < FM; ++m)
#pragma unroll
        for (int n = 0; n < FN; ++n) acc[m][n] = (f32x4){0.f, 0.f, 0.f, 0.f};
    gemm_kloop<FM, FN>(As, Bs, A, B, acc, K, 0, K / 32, bm, bn);
    const int lane = threadIdx.x & 63, wid = threadIdx.x >> 6;
    const int l15 = lane & 15, lg = lane >> 4;
    const int r0 = bm + (wid >> 1) * FM * 16, c0 = bn + (wid & 1) * FN * 16;
#pragma unroll
    for (int m = 0; m < FM; ++m)
#pragma unroll
        for (int n = 0; n < FN; ++n)
#pragma unroll
            for (int j = 0; j < 4; ++j) {
                int row = r0 + m * 16 + lg * 4 + j;
                int col = c0 + n * 16 + l15;
                if (row < M && col < N) {
                    float v = acc[m][n][j] + (bias ? bias[col] : 0.f);
                    if (relu) v = fmaxf(v, 0.f);
                    if (C)  C[(size_t)row * N + col] = v;
                    if (Cb) Cb[(size_t)row * N + col] = f2b(v);
                }
            }
}

// split-K: grid.z splits accumulate via f32 atomicAdd into pre-zeroed C
template <int FM, int FN, bool SWZ = false>
__global__ __launch_bounds__(256) void gemm_splitk(const ushort_t* __restrict__ A,
                                                   const ushort_t* __restrict__ B,
                                                   float* __restrict__ C,
                                                   int M, int N, int K, int S) {
    __shared__ ushort_t As[FM * 32 * 32];
    __shared__ ushort_t Bs[FN * 32 * 32];
    int bx, by, bz;
    get_bxyz<SWZ>(bx, by, bz);
    const int nsteps = K / 32;
    const int ss = (nsteps + S - 1) / S;
    const int ks0 = bz * ss;
    const int ks1 = min(nsteps, ks0 + ss);
    if (ks0 >= ks1) return;
    const int bm = by * FM * 32, bn = bx * FN * 32;
    f32x4 acc[FM][FN];
#pragma unroll
    for (int m = 0; m < FM; ++m)
#pragma unroll
        for (int n = 0; n < FN; ++n) acc[m][n] = (f32x4){0.f, 0.f, 0.f, 0.f};
    gemm_kloop<FM, FN>(As, Bs, A, B, acc, K, ks0, ks1, bm, bn);
    const int lane = threadIdx.x & 63, wid = threadIdx.x >> 6;
    const int l15 = lane & 15, lg = lane >> 4;
    const int r0 = bm + (wid >> 1) * FM * 16, c0 = bn + (wid & 1) * FN * 16;
#pragma unroll
    for (int m = 0; m < FM; ++m)
#pragma unroll
        for (int n = 0; n < FN; ++n)
#pragma unroll
            for (int j = 0; j < 4; ++j) {
                int row = r0 + m * 16 + lg * 4 + j;
                int col = c0 + n * 16 + l15;
                if (row < M && col < N)
                    atomicAdd(&C[(size_t)row * N + col], acc[m][n][j]);
            }
}

// ---------------- fused ghe-GEMM + edge GRU ----------------
// Block (x,y): rows [y*64, y*64+64), d-cols [x*32, x*32+32) across ALL 3 gates
// (weight rows {g*512 + d}). Epilogue applies GRU, writes double-buffered es.
// A = esb_in [E][512]; W = egwhhb [1536][512]; gi = gie [E][1536].
__global__ __launch_bounds__(256) void k_ghe_gru(const ushort_t* __restrict__ esb_in,
                                                 const ushort_t* __restrict__ W,
                                                 const float* __restrict__ gi,
                                                 const float* __restrict__ es_in,
                                                 float* __restrict__ es_out,
                                                 ushort_t* __restrict__ esb_out) {
    __shared__ ushort_t As[64 * 32];
    __shared__ ushort_t Bs[96 * 32];
    // swizzle: nx=16, ny=48 (ny%8==0)
    int bid = blockIdx.x + gridDim.x * blockIdx.y;
    int r8 = bid & 7, i = bid >> 3;
    int per = gridDim.x;
    int ygrp = i / per;
    int x = i - ygrp * per;
    int y = r8 + 8 * ygrp;
    const int bm = y * 64;
    const int dcol0 = x * 32;
    const int tid = threadIdx.x;
    const int lane = tid & 63, wid = tid >> 6;
    const int wr = wid >> 1, wc = wid & 1;
    const int ar = tid >> 2, ac = (tid & 3) * 8;
    const int l15 = lane & 15, lg = lane >> 4;
    f32x4 acc[2][3];
#pragma unroll
    for (int m = 0; m < 2; ++m)
#pragma unroll
        for (int g = 0; g < 3; ++g) acc[m][g] = (f32x4){0.f, 0.f, 0.f, 0.f};

    for (int k0 = 0; k0 < D_; k0 += 32) {
        GLOAD_LDS16(esb_in + (size_t)(bm + ar) * D_ + k0 + ac, &As[ar * 32 + ac]);
        {   // B rows 0..63 (gates 0,1)
            int rr = ar;
            int wrow = (rr >> 5) * D_ + dcol0 + (rr & 31);
            GLOAD_LDS16(W + (size_t)wrow * D_ + k0 + ac, &Bs[rr * 32 + ac]);
        }
        if (tid < 128) {  // B rows 64..95 (gate 2), wave-uniform predicate
            int rr = 64 + ar;
            int wrow = 2 * D_ + dcol0 + (rr & 31);
            GLOAD_LDS16(W + (size_t)wrow * D_ + k0 + ac, &Bs[rr * 32 + ac]);
        }
        __syncthreads();
        sh8 af[2], bf[3];
#pragma unroll
        for (int m = 0; m < 2; ++m)
            af[m] = *(const sh8*)&As[(wr * 32 + m * 16 + l15) * 32 + lg * 8];
#pragma unroll
        for (int g = 0; g < 3; ++g)
            bf[g] = *(const sh8*)&Bs[(g * 32 + wc * 16 + l15) * 32 + lg * 8];
#pragma unroll
        for (int m = 0; m < 2; ++m)
#pragma unroll
            for (int g = 0; g < 3; ++g)
                acc[m][g] = __builtin_amdgcn_mfma_f32_16x16x32_bf16(af[m], bf[g], acc[m][g], 0, 0, 0);
        __syncthreads();
    }

    const int d = dcol0 + wc * 16 + l15;
#pragma unroll
    for (int m = 0; m < 2; ++m)
#pragma unroll
        for (int j = 0; j < 4; ++j) {
            int row = bm + wr * 32 + m * 16 + lg * 4 + j;
            size_t gbase = (size_t)row * 1536 + d;
            float r = 1.f / (1.f + expf(-(gi[gbase] + acc[m][0][j])));
            float z = 1.f / (1.f + expf(-(gi[gbase + 512] + acc[m][1][j])));
            float g = tanhf(gi[gbase + 1024] + r * acc[m][2][j]);
            float hv = es_in[(size_t)row * D_ + d];
            float nv = (1.f - z) * g + z * hv;
            es_out[(size_t)row * D_ + d] = nv;
            esb_out[(size_t)row * D_ + d] = f2b(nv);
        }
}

static inline dim3 mgrid(int M, int N, int FM, int FN) {
    return dim3((N + FN * 32 - 1) / (FN * 32), (M + FM * 32 - 1) / (FM * 32));
}
static inline dim3 sgrid(int M, int N, int FM, int FN, int S) {
    dim3 g = mgrid(M, N, FM, FN);
    return dim3(g.x, g.y, S);
}

extern "C" void kernel_launch(void* const* d_in, const int* in_sizes, int n_in,
                              void* d_out, int out_size, void* d_ws, size_t ws_size,
                              hipStream_t stream) {
    const float* x      = (const float*)d_in[0];
    const float* posi   = (const float*)d_in[1];
    const float* unionf = (const float*)d_in[2];
    const int*   lab    = (const int*)d_in[3];
    const int*   rp     = (const int*)d_in[4];
    const float* emb1   = (const float*)d_in[5];
    const float* emb2   = (const float*)d_in[6];
    const float* nw     = (const float*)d_in[7];
    const float* nb     = (const float*)d_in[8];
    const float* nw2    = (const float*)d_in[9];
    const float* nb2    = (const float*)d_in[10];
    const float* ew     = (const float*)d_in[11];
    const float* eb     = (const float*)d_in[12];
    const float* pw1    = (const float*)d_in[13];
    const float* pb1    = (const float*)d_in[14];
    const float* pg     = (const float*)d_in[15];
    const float* pbe    = (const float*)d_in[16];
    const float* pw2    = (const float*)d_in[17];
    const float* pb2    = (const float*)d_in[18];
    const float* ngwih  = (const float*)d_in[19];
    const float* ngwhh  = (const float*)d_in[20];
    const float* ngbih  = (const float*)d_in[21];
    const float* ngbhh  = (const float*)d_in[22];
    const float* egwih  = (const float*)d_in[23];
    const float* egwhh  = (const float*)d_in[24];
    const float* n2nw1  = (const float*)d_in[25];
    const float* n2nb1  = (const float*)d_in[26];
    const float* n2nw2  = (const float*)d_in[27];
    const float* n2nb2  = (const float*)d_in[28];
    const float* e2nw1  = (const float*)d_in[29];
    const float* e2nb1  = (const float*)d_in[30];
    const float* e2nw2  = (const float*)d_in[31];
    const float* e2nb2  = (const float*)d_in[32];
    const float* n2ew1  = (const float*)d_in[33];
    const float* n2eb1  = (const float*)d_in[34];
    const float* n2ew2  = (const float*)d_in[35];
    const float* n2eb2  = (const float*)d_in[36];
    const float* relw   = (const float*)d_in[37];
    const float* relb   = (const float*)d_in[38];

    size_t off = 0;
    auto alloc = [&](size_t bytes) {
        off = (off + 255) & ~(size_t)255;
        char* p = (char*)d_ws + off;
        off += bytes;
        return (void*)p;
    };
    int*      mapMin  = (int*)alloc((size_t)N_ * N_ * 4);
    int*      rep     = (int*)alloc(E_ * 4);
    int*      deg_cnt = (int*)alloc(N_ * 4);
    float*    inv_deg = (float*)alloc(N_ * 4);
    float*    posn    = (float*)alloc(N_ * 32 * 4);
    float*    pe      = (float*)alloc(N_ * 128 * 4);
    float*    ns      = (float*)alloc((size_t)N_ * D_ * 4);
    ushort_t* nsb     = (ushort_t*)alloc((size_t)N_ * D_ * 2);
    float*    nsraw   = (float*)alloc((size_t)N_ * D_ * 4);
    // scratch region: [n2n | tmpraw | n2nmraw | gin | ghn] -- one memset per use
    char*     scrR    = (char*)alloc((size_t)(3 * N_ * D_ + 2 * N_ * 3 * D_) * 4);
    float*    n2n     = (float*)scrR;
    float*    tmpraw  = (float*)(scrR + (size_t)N_ * D_ * 4);
    float*    n2nmraw = (float*)(scrR + (size_t)2 * N_ * D_ * 4);
    float*    gin     = (float*)(scrR + (size_t)3 * N_ * D_ * 4);
    float*    ghn     = (float*)(scrR + (size_t)(3 * N_ * D_ + N_ * 3 * D_) * 4);
    const size_t scrBytes = (size_t)(3 * N_ * D_ + 2 * N_ * 3 * D_) * 4;
    float*    e2nm    = (float*)alloc((size_t)N_ * D_ * 4);
    float*    relraw  = (float*)alloc((size_t)E_ * 64 * 4);
    // union: A1b / A2b / ekb -- sequential lifetimes
    char*     unionU  = (char*)alloc((size_t)E_ * 2 * D_ * 2);
    ushort_t* A1b = (ushort_t*)unionU;
    ushort_t* A2b = (ushort_t*)unionU;
    ushort_t* ekb = (ushort_t*)unionU;
    // union: ufb bf16 (early) / gie f32 (late)
    char*     ufbU = (char*)alloc((size_t)E_ * CIN_ * 2);
    ushort_t* ufb = (ushort_t*)ufbU;
    float*    gie = (float*)ufbU;
    // union: erep f32 (early) / erepb+msgb bf16 (late)
    char*     erepU = (char*)alloc((size_t)E_ * D_ * 4);
    float*    erep  = (float*)erepU;
    ushort_t* erepb = (ushort_t*)erepU;
    ushort_t* msgb  = (ushort_t*)(erepU + (size_t)E_ * D_ * 2);
    float*    es    = (float*)alloc((size_t)E_ * D_ * 4);
    ushort_t* esb   = (ushort_t*)alloc((size_t)E_ * D_ * 2);
    float*    es2   = (float*)alloc((size_t)E_ * D_ * 4);   // GRU double buffer
    ushort_t* esb2  = (ushort_t*)alloc((size_t)E_ * D_ * 2);
    float*    e2n   = (float*)alloc((size_t)N_ * D_ * 4);
    ushort_t* e2nb  = (ushort_t*)alloc((size_t)N_ * D_ * 2);
    ushort_t* tmpb  = (ushort_t*)alloc((size_t)N_ * D_ * 2);
    ushort_t* n2nb  = (ushort_t*)alloc((size_t)N_ * D_ * 2);
    ushort_t* xinb  = (ushort_t*)alloc((size_t)N_ * D_ * 2);
    // bf16 weights
    ushort_t* nwb     = (ushort_t*)alloc((size_t)D_ * K1P_ * 2);
    ushort_t* nw2b    = (ushort_t*)alloc((size_t)D_ * K2P_ * 2);
    ushort_t* ewb     = (ushort_t*)alloc((size_t)D_ * CIN_ * 2);
    ushort_t* ngwihb  = (ushort_t*)alloc((size_t)3 * D_ * D_ * 2);
    ushort_t* ngwhhb  = (ushort_t*)alloc((size_t)3 * D_ * D_ * 2);
    ushort_t* egwihb  = (ushort_t*)alloc((size_t)3 * D_ * D_ * 2);
    ushort_t* egwhhb  = (ushort_t*)alloc((size_t)3 * D_ * D_ * 2);
    ushort_t* n2nw1b  = (ushort_t*)alloc((size_t)D_ * D_ * 2);
    ushort_t* n2nw2b  = (ushort_t*)alloc((size_t)D_ * D_ * 2);
    ushort_t* e2nw1b  = (ushort_t*)alloc((size_t)D_ * D_ * 2);
    ushort_t* e2nw2b  = (ushort_t*)alloc((size_t)D_ * D_ * 2);
    ushort_t* n2ew1b  = (ushort_t*)alloc((size_t)D_ * 2 * D_ * 2);
    ushort_t* n2ew2b  = (ushort_t*)alloc((size_t)D_ * D_ * 2);
    ushort_t* relwb   = (ushort_t*)alloc((size_t)64 * D_ * 2);
    if (off > ws_size) return;

    float* out_obj = (float*)d_out;
    float* out_rel = (float*)d_out + N_ * NOBJ_;

    // ---- weight + union_features bf16 conversion ----
    ConvArgs ca;
    int ci = 0;
    auto addc = [&](const float* s, ushort_t* dptr, int K, int Kp, int rows, int rowsp) {
        ca.d[ci++] = ConvDesc{s, dptr, K, Kp, rows, rowsp};
    };
    addc(nw,    nwb,    K1_,      K1P_,     D_,       D_);
    addc(nw2,   nw2b,   K2_,      K2P_,     D_,       D_);
    addc(ew,    ewb,    CIN_,     CIN_,     D_,       D_);
    addc(ngwih, ngwihb, D_,       D_,       3 * D_,   3 * D_);
    addc(ngwhh, ngwhhb, D_,       D_,       3 * D_,   3 * D_);
    addc(egwih, egwihb, D_,       D_,       3 * D_,   3 * D_);
    addc(egwhh, egwhhb, D_,       D_,       3 * D_,   3 * D_);
    addc(n2nw1, n2nw1b, D_,       D_,       D_,       D_);
    addc(n2nw2, n2nw2b, D_,       D_,       D_,       D_);
    addc(e2nw1, e2nw1b, D_,       D_,       D_,       D_);
    addc(e2nw2, e2nw2b, D_,       D_,       D_,       D_);
    addc(n2ew1, n2ew1b, 2 * D_,   2 * D_,   D_,       D_);
    addc(n2ew2, n2ew2b, D_,       D_,       D_,       D_);
    addc(relw,  relwb,  D_,       D_,       NREL_,    64);
    addc(unionf, ufb,   CIN_,     CIN_,     E_,       E_);
    for (; ci < 16;) ca.d[ci++] = ConvDesc{nullptr, nullptr, 4, 4, 0, 0};
    k_conv_batch<<<dim3(512, 15), 256, 0, stream>>>(ca);

    // ---- pair dedup + degrees ----
    (void)hipMemsetAsync(mapMin, 0x7F, (size_t)N_ * N_ * 4, stream);
    (void)hipMemsetAsync(deg_cnt, 0, N_ * 4, stream);
    k_pair_min<<<(E_ + 255) / 256, 256, 0, stream>>>(rp, mapMin);
    k_pair_rep<<<(E_ + 255) / 256, 256, 0, stream>>>(rp, mapMin, rep, deg_cnt);
    k_inv_deg<<<(N_ + 255) / 256, 256, 0, stream>>>(deg_cnt, inv_deg);

    // ---- pos embed ----
    k_pos_a<<<1, 1024, 0, stream>>>(posi, pw1, pb1, pg, pbe, posn);
    k_pos2<<<(N_ * 128 + 255) / 256, 256, 0, stream>>>(posn, pw2, pb2, pe);

    // ---- node_states = [x|emb1|pos] @ nw^T + nb (split-K S=8) ----
    k_build_A1b<<<((size_t)N_ * K1P_ + 255) / 256, 256, 0, stream>>>(x, lab, emb1, pe, A1b);
    (void)hipMemsetAsync(nsraw, 0, (size_t)N_ * D_ * 4, stream);
    gemm_splitk<1, 1><<<sgrid(N_, D_, 1, 1, 8), 256, 0, stream>>>(A1b, nwb, nsraw, N_, D_, K1P_, 8);
    k_epi<<<(N_ * D_ + 255) / 256, 256, 0, stream>>>(nsraw, nb, ns, nsb, N_ * D_, D_ - 1, 0);

    // ---- edge_rep (split-K S=4 + XCD swizzle) + sparse edge_states ----
    (void)hipMemsetAsync(erep, 0, (size_t)E_ * D_ * 4, stream);
    gemm_splitk<2, 2, true><<<sgrid(E_, D_, 2, 2, 4), 256, 0, stream>>>(ufb, ewb, erep, E_, D_, CIN_, 4);
    k_epi<<<((size_t)E_ * D_ + 255) / 256, 256, 0, stream>>>(erep, eb, erep, nullptr, E_ * D_, D_ - 1, 0);
    (void)hipMemsetAsync(es, 0, (size_t)E_ * D_ * 4, stream);
    k_scatter_edge<<<dim3(E_, 2), 256, 0, stream>>>(erep, rep, es);
    k_broadcast_es<<<(E_ * D_ + 255) / 256, 256, 0, stream>>>(rep, es, esb);

    // ---- e2n (loop-invariant): scatter + split-K MLP ----
    (void)hipMemsetAsync(e2n, 0, (size_t)N_ * D_ * 4, stream);
    k_scatter_e2n<<<dim3(E_, 2), 256, 0, stream>>>(rp, rep, es, e2n);
    k_f2b_n<<<(N_ * D_ + 255) / 256, 256, 0, stream>>>(e2n, e2nb, N_ * D_);
    (void)hipMemsetAsync(scrR, 0, scrBytes, stream);
    gemm_splitk<1, 1><<<sgrid(N_, D_, 1, 1, 8), 256, 0, stream>>>(e2nb, e2nw1b, tmpraw, N_, D_, D_, 8);
    k_epi<<<(N_ * D_ + 255) / 256, 256, 0, stream>>>(tmpraw, e2nb1, nullptr, tmpb, N_ * D_, D_ - 1, 1);
    gemm_splitk<1, 1><<<sgrid(N_, D_, 1, 1, 8), 256, 0, stream>>>(tmpb, e2nw2b, n2nmraw, N_, D_, D_, 8);
    k_epi<<<(N_ * D_ + 255) / 256, 256, 0, stream>>>(n2nmraw, e2nb2, e2nm, nullptr, N_ * D_, D_ - 1, 1);

    // ---- node GRU loop x3 ----
    for (int it = 0; it < 3; ++it) {
        (void)hipMemsetAsync(scrR, 0, scrBytes, stream);
        k_scatter_n2n<<<dim3(E_, 2), 256, 0, stream>>>(rp, rep, ns, n2n);
        k_scale_rows_b<<<(N_ * D_ + 255) / 256, 256, 0, stream>>>(n2n, inv_deg, n2nb);
        gemm_splitk<1, 1><<<sgrid(N_, D_, 1, 1, 8), 256, 0, stream>>>(n2nb, n2nw1b, tmpraw, N_, D_, D_, 8);
        k_epi<<<(N_ * D_ + 255) / 256, 256, 0, stream>>>(tmpraw, n2nb1, nullptr, tmpb, N_ * D_, D_ - 1, 1);
        gemm_splitk<1, 1><<<sgrid(N_, D_, 1, 1, 8), 256, 0, stream>>>(tmpb, n2nw2b, n2nmraw, N_, D_, D_, 8);
        k_combine_b<<<(N_ * D_ + 255) / 256, 256, 0, stream>>>(n2nmraw, n2nb2, e2nm, xinb);
        gemm_splitk<1, 1><<<sgrid(N_, 3 * D_, 1, 1, 4), 256, 0, stream>>>(xinb, ngwihb, gin, N_, 3 * D_, D_, 4);
        gemm_splitk<1, 1><<<sgrid(N_, 3 * D_, 1, 1, 4), 256, 0, stream>>>(nsb, ngwhhb, ghn, N_, 3 * D_, D_, 4);
        k_gru<<<(N_ * D_ + 255) / 256, 256, 0, stream>>>(gin, ghn, ngbih, ngbhh, ns, nsb, N_);
    }

    // ---- obj_dists ----
    k_obj_dists<<<(N_ * NOBJ_ + 255) / 256, 256, 0, stream>>>(lab, out_obj);

    // ---- node_states2 (split-K S=8) ----
    k_build_A2b<<<((size_t)N_ * K2P_ + 255) / 256, 256, 0, stream>>>(x, lab, emb2, nsb, A2b);
    (void)hipMemsetAsync(nsraw, 0, (size_t)N_ * D_ * 4, stream);
    gemm_splitk<1, 1><<<sgrid(N_, D_, 1, 1, 8), 256, 0, stream>>>(A2b, nw2b, nsraw, N_, D_, K2P_, 8);
    k_epi<<<(N_ * D_ + 255) / 256, 256, 0, stream>>>(nsraw, nb2, ns, nsb, N_ * D_, D_ - 1, 0);

    // ---- edge loop: msg + gi loop-invariant; GRU fused into ghe GEMM ----
    k_build_ekb<<<((size_t)E_ * 2 * D_ + 255) / 256, 256, 0, stream>>>(rp, nsb, ekb);
    gemm_mfma<2, 2, true><<<mgrid(E_, D_, 2, 2), 256, 0, stream>>>(ekb, n2ew1b, n2eb1, nullptr, erepb, E_, D_, 2 * D_, 1);
    gemm_mfma<2, 2, true><<<mgrid(E_, D_, 2, 2), 256, 0, stream>>>(erepb, n2ew2b, n2eb2, nullptr, msgb, E_, D_, D_, 1);
    gemm_mfma<2, 4, true><<<mgrid(E_, 3 * D_, 2, 4), 256, 0, stream>>>(msgb, egwihb, nullptr, gie, nullptr, E_, 3 * D_, D_, 0);
    {
        float* esI = es;  ushort_t* esbI = esb;
        float* esO = es2; ushort_t* esbO = esb2;
        for (int it = 0; it < 3; ++it) {
            k_ghe_gru<<<dim3(16, 48), 256, 0, stream>>>(esbI, egwhhb, gie, esI, esO, esbO);
            float* tf = esI; esI = esO; esO = tf;
            ushort_t* tb = esbI; esbI = esbO; esbO = tb;
        }
        // result now in esI/esbI (= es2/esb2 after 3 swaps)
        // ---- rel_dists: split-K into padded raw, then bias epilogue ----
        (void)hipMemsetAsync(relraw, 0, (size_t)E_ * 64 * 4, stream);
        gemm_splitk<1, 1><<<sgrid(E_, 64, 1, 1, 4), 256, 0, stream>>>(esbI, relwb, relraw, E_, 64, D_, 4);
        k_epi_rel<<<(E_ * NREL_ + 255) / 256, 256, 0, stream>>>(relraw, relb, out_rel);
    }
}